// Round 6
// baseline (1028.868 us; speedup 1.0000x reference)
//
#include <hip/hip_runtime.h>
#include <math.h>

#define NB 256
#define NS 512
#define ND 256
#define NL 4
#define NITERS 10
#define DD (ND*ND)      // 65536
#define KCH 64          // k-chunk for stage
#define BPAD 65         // Bs row stride [32 cols][65]
#define APAD 772        // As row stride (772%32=4 -> 4r bank spread)

// ---------------------------------------------------------------------------
// K1: partial[(4b+q)][d] = sum over 128 s of emb[ids[b,s]][d] + pos[s][d]
// ---------------------------------------------------------------------------
__global__ __launch_bounds__(256) void k_pool1(const int* __restrict__ ids,
                                               const float* __restrict__ emb,
                                               const float* __restrict__ pos,
                                               float* __restrict__ partial) {
    const int bid = blockIdx.x;
    const int b = bid >> 2, q = bid & 3;
    const int t = threadIdx.x;
    __shared__ int sid[128];
    if (t < 128) sid[t] = ids[b * NS + q * 128 + t];
    __syncthreads();
    float acc = 0.f;
#pragma unroll 8
    for (int s = 0; s < 128; ++s)
        acc += emb[(size_t)sid[s] * ND + t] + pos[(q * 128 + s) * ND + t];
    partial[bid * ND + t] = acc;
}

// ---------------------------------------------------------------------------
// k_prep: combined matrices now stored ROW-MAJOR [d][k] (natural Linear-W
// layout) so k_stage can stage B as [col][k] and read b128 along k.
//   CM slots: 0:G0 1:H0 3:U1 4:G1 5:H1 6:U2 7:G2 8:H2 9:U3 10:G3
//   G_l = 0.5U_l - U_l P_l (l<3), G3 = -U3 P3, H_l = -0.5 U_l P_{l+1}
//   (U P)[d,k] = sum_e U[d,e] P[e,k]
//   KSt/KEt/rc0/CMI keep their old layouts (consumers unchanged).
// ---------------------------------------------------------------------------
__global__ __launch_bounds__(256) void k_prep(
    const float* __restrict__ pred_w, const float* __restrict__ pred_b,
    const float* __restrict__ upd_w,  const float* __restrict__ upd_b,
    const float* __restrict__ init_w,
    const float* __restrict__ sw, const float* __restrict__ sb,
    const float* __restrict__ ew, const float* __restrict__ eb,
    const float* __restrict__ kw, const float* __restrict__ kb,
    const float* __restrict__ w1,
    const float* __restrict__ partial,
    float* __restrict__ CM, float* __restrict__ CMI,
    float* __restrict__ KSt, float* __restrict__ KEt, float* __restrict__ W1t,
    float* __restrict__ cvec, float* __restrict__ rc0,
    float* __restrict__ vsk, float* __restrict__ vse,
    float* __restrict__ ksb, float* __restrict__ keb, float* __restrict__ scal)
{
    const int bid = blockIdx.x;
    const int t = threadIdx.x;

    if (bid < 576 || (bid >= 1056 && bid < 1120)) {
        // GEMM blocks: OUT[i][j] = alpha * sum_e Aop(i,e)*Bop(e,j) + tau*Asrc[i][j]
        int id, tile;
        if (bid < 576) { id = bid >> 6; tile = bid & 63; }
        else           { id = 9;        tile = bid - 1056; }
        const float* Asrc = nullptr; const float* Bsrc = nullptr;
        float alpha = 1.f, tau = 0.f; float* outp = nullptr;
        int aMode = 0, bMode = 0;  // aMode: 0 row-major A[i][e], 1 col-major A[e][i], 2 pooled
        switch (id) {
            case 0: Asrc = upd_w;        Bsrc = pred_w;        alpha=-1.f;  tau=0.5f; outp = CM + 0*(size_t)DD; break;
            case 1: Asrc = upd_w;        Bsrc = pred_w + DD;   alpha=-0.5f;           outp = CM + 1*(size_t)DD; break;
            case 2: Asrc = upd_w + DD;   Bsrc = pred_w + DD;   alpha=-1.f;  tau=0.5f; outp = CM + 4*(size_t)DD; break;
            case 3: Asrc = upd_w + DD;   Bsrc = pred_w + 2*DD; alpha=-0.5f;           outp = CM + 5*(size_t)DD; break;
            case 4: Asrc = upd_w + 2*DD; Bsrc = pred_w + 2*DD; alpha=-1.f;  tau=0.5f; outp = CM + 7*(size_t)DD; break;
            case 5: Asrc = upd_w + 2*DD; Bsrc = pred_w + 3*DD; alpha=-0.5f;           outp = CM + 8*(size_t)DD; break;
            case 6: Asrc = upd_w + 3*DD; Bsrc = pred_w + 3*DD; alpha=-1.f;            outp = CM + 10*(size_t)DD; break;
            case 7: Asrc = sw; Bsrc = kw; aMode = 1; outp = KSt; break;
            case 8: Asrc = ew; Bsrc = kw; aMode = 1; outp = KEt; break;
            default: Bsrc = upd_w; aMode = 2; bMode = 1; outp = rc0; break;
        }
        const int i0 = (tile >> 3) * 32, j0 = (tile & 7) * 32;
        __shared__ float As[32 * 33];
        __shared__ float Bs[32 * 33];
        const int tx = t & 15, ty = t >> 4;
        float a00 = 0.f, a01 = 0.f, a10 = 0.f, a11 = 0.f;
        for (int e0 = 0; e0 < 256; e0 += 32) {
            __syncthreads();
            if (aMode == 0) {       // As[e][i] = A[i][e], lanes-e coalesced
                const int ee = t & 31, i8 = t >> 5;
#pragma unroll
                for (int p = 0; p < 4; ++p) {
                    int ii = i8 + 8 * p;
                    As[ee * 33 + ii] = Asrc[(size_t)(i0 + ii) * 256 + e0 + ee];
                }
            } else if (aMode == 1) { // As[e][i] = A[e][i], lanes-i coalesced
                const int ii = t & 31, e8 = t >> 5;
#pragma unroll
                for (int p = 0; p < 4; ++p) {
                    int ee = e8 + 8 * p;
                    As[ee * 33 + ii] = Asrc[(size_t)(e0 + ee) * 256 + i0 + ii];
                }
            } else {                 // pooled rows from partial
                const int ee = t & 31, i8 = t >> 5;
#pragma unroll
                for (int p = 0; p < 4; ++p) {
                    int ii = i8 + 8 * p;
                    const float* pp = partial + (size_t)(i0 + ii) * 4 * 256 + e0 + ee;
                    As[ee * 33 + ii] = (pp[0] + pp[256] + pp[512] + pp[768]) * (1.f / 512.f);
                }
            }
            if (bMode == 0) {       // Bs[e][j] = B[e][j], lanes-j coalesced
                const int jj = t & 31, e8 = t >> 5;
#pragma unroll
                for (int p = 0; p < 4; ++p) {
                    int ee = e8 + 8 * p;
                    Bs[ee * 33 + jj] = Bsrc[(size_t)(e0 + ee) * 256 + j0 + jj];
                }
            } else {                 // Bs[e][j] = B[j][e], lanes-e coalesced
                const int ee = t & 31, j8 = t >> 5;
#pragma unroll
                for (int p = 0; p < 4; ++p) {
                    int jj = j8 + 8 * p;
                    Bs[ee * 33 + jj] = Bsrc[(size_t)(j0 + jj) * 256 + e0 + ee];
                }
            }
            __syncthreads();
#pragma unroll
            for (int e = 0; e < 32; ++e) {
                float va0 = As[e * 33 + 2 * ty], va1 = As[e * 33 + 2 * ty + 1];
                float vb0 = Bs[e * 33 + 2 * tx], vb1 = Bs[e * 33 + 2 * tx + 1];
                a00 += va0 * vb0; a01 += va0 * vb1;
                a10 += va1 * vb0; a11 += va1 * vb1;
            }
        }
        float t00 = 0.f, t01 = 0.f, t10 = 0.f, t11 = 0.f;
        if (tau != 0.f) { // tau term is +tau*Asrc[i][j]
            t00 = Asrc[(size_t)(i0 + 2 * ty) * 256 + j0 + 2 * tx];
            t01 = Asrc[(size_t)(i0 + 2 * ty) * 256 + j0 + 2 * tx + 1];
            t10 = Asrc[(size_t)(i0 + 2 * ty + 1) * 256 + j0 + 2 * tx];
            t11 = Asrc[(size_t)(i0 + 2 * ty + 1) * 256 + j0 + 2 * tx + 1];
        }
        outp[(size_t)(i0 + 2 * ty) * 256 + j0 + 2 * tx]         = alpha * a00 + tau * t00;
        outp[(size_t)(i0 + 2 * ty) * 256 + j0 + 2 * tx + 1]     = alpha * a01 + tau * t01;
        outp[(size_t)(i0 + 2 * ty + 1) * 256 + j0 + 2 * tx]     = alpha * a10 + tau * t10;
        outp[(size_t)(i0 + 2 * ty + 1) * 256 + j0 + 2 * tx + 1] = alpha * a11 + tau * t11;
        return;
    }

    if (bid < 1024) {
        const int tid = bid - 576;
        const int m = tid >> 6, tile = tid & 63;
        const int r0 = (tile >> 3) * 32, c0 = (tile & 7) * 32;
        if (m < 3) {
            // U_{m+1} -> CM slot 3+3m, straight row-major copy (no transpose)
            const float* src = upd_w + (size_t)(m + 1) * DD;
            float* dst = CM + (size_t)(3 + 3 * m) * DD;
            const int cc = t & 31, r8 = t >> 5;
#pragma unroll
            for (int p = 0; p < 4; ++p) {
                int rr = r8 + 8 * p;
                dst[(size_t)(r0 + rr) * 256 + c0 + cc] = src[(size_t)(r0 + rr) * 256 + c0 + cc];
            }
        } else {
            // init_w transposes -> CMI (k_init consumes [k][d])
            const float* src = init_w + (size_t)(m - 3) * DD;
            float* dst = CMI + (size_t)(m - 3) * DD;
            __shared__ float T[32 * 33];
            const int cc = t & 31, r8 = t >> 5;
#pragma unroll
            for (int p = 0; p < 4; ++p) {
                int rr = r8 + 8 * p;
                T[rr * 33 + cc] = src[(size_t)(r0 + rr) * 256 + c0 + cc];
            }
            __syncthreads();
#pragma unroll
            for (int p = 0; p < 4; ++p) {
                int rr = r8 + 8 * p;
                dst[(size_t)(c0 + rr) * 256 + r0 + cc] = T[cc * 33 + rr];
            }
        }
        return;
    }

    if (bid < 1056) {
        // w1 [128][256] -> W1t [256][128]
        const int tile = bid - 1024;
        const int e0 = (tile >> 2) * 32, j0 = (tile & 3) * 32;
        __shared__ float T[32 * 33];
        const int cc = t & 31, r8 = t >> 5;
#pragma unroll
        for (int p = 0; p < 4; ++p) {
            int jj = r8 + 8 * p;
            T[jj * 33 + cc] = w1[(size_t)(j0 + jj) * 256 + e0 + cc];
        }
        __syncthreads();
#pragma unroll
        for (int p = 0; p < 4; ++p) {
            int ee = r8 + 8 * p;
            W1t[(size_t)(e0 + ee) * 128 + j0 + cc] = T[cc * 33 + ee];
        }
        return;
    }

    const int vb = bid - 1120;
    if (vb < 4) { // c_l[d] = ub_l[d] - sum_k U_l[d][k]*(pb_l[k] + 0.5*pb_{l+1}[k])
        const int l = vb;
        __shared__ float v[256];
        v[t] = (l < 3) ? pred_b[l * 256 + t] + 0.5f * pred_b[(l + 1) * 256 + t]
                       : pred_b[3 * 256 + t];
        __syncthreads();
        const float* U = upd_w + (size_t)l * DD + (size_t)t * 256;
        float acc = 0.f;
#pragma unroll 8
        for (int k = 0; k < 256; k += 4) {
            float4 u = *(const float4*)&U[k];
            acc += u.x * v[k] + u.y * v[k + 1] + u.z * v[k + 2] + u.w * v[k + 3];
        }
        cvec[l * 256 + t] = upd_b[l * 256 + t] - acc;
        return;
    }
    {
        const float* W = (vb == 4) ? sw : ew;
        const float* bb = (vb == 4) ? sb : eb;
        float* vout = (vb == 4) ? vsk : vse;
        float* bout = (vb == 4) ? ksb : keb;
        __shared__ float kbv[256], bbv[256], red[256];
        kbv[t] = kb[t]; bbv[t] = bb[t];
        __syncthreads();
        float a1 = 0.f, a2 = 0.f;
#pragma unroll 4
        for (int k = 0; k < 256; ++k) {
            a1 += W[(size_t)k * 256 + t] * kbv[k];
            a2 += kw[(size_t)k * 256 + t] * bbv[k];
        }
        vout[t] = a1; bout[t] = a2;
        red[t] = kbv[t] * bbv[t];
        __syncthreads();
        for (int s = 128; s > 0; s >>= 1) {
            if (t < s) red[t] += red[t + s];
            __syncthreads();
        }
        if (t == 0) scal[vb - 4] = red[0];
        return;
    }
}

// ---------------------------------------------------------------------------
// k_init: per-row init chain using transposed init weights (coalesced).
// ---------------------------------------------------------------------------
__global__ __launch_bounds__(256) void k_init(const float* __restrict__ partial,
                                              const float* __restrict__ CMI,
                                              const float* __restrict__ init_b,
                                              float* __restrict__ rA,
                                              float* __restrict__ ff)
{
    const int row = blockIdx.x, t = threadIdx.x;
    __shared__ float xs[256];
    {
        const float* p = partial + (size_t)row * 4 * 256 + t;
        xs[t] = (p[0] + p[256] + p[512] + p[768]) * (1.f / 512.f);
    }
    float* rrow = rA + (size_t)row * 1024;
    for (int il = 0; il < 4; ++il) {
        __syncthreads();
        const float* M = CMI + (size_t)il * DD + t;
        float a0 = 0.f, a1 = 0.f, a2 = 0.f, a3 = 0.f;
#pragma unroll 8
        for (int k = 0; k < 256; k += 4) {
            float4 xv = *(const float4*)&xs[k];
            a0 += M[(size_t)(k + 0) * 256] * xv.x;
            a1 += M[(size_t)(k + 1) * 256] * xv.y;
            a2 += M[(size_t)(k + 2) * 256] * xv.z;
            a3 += M[(size_t)(k + 3) * 256] * xv.w;
        }
        float vx = tanhf(a0 + a1 + a2 + a3 + init_b[il * 256 + t]);
        __syncthreads();
        xs[t] = vx;
        rrow[il * 256 + t] = vx;
        if (il == 3) ff[(size_t)row * 256 + t] = vx;
    }
}

// ---------------------------------------------------------------------------
// k_stage v3: one refinement iteration, VALU-balanced tiled GEMM.
// grid 1024 = 32 rowtiles(8 rows) x (4 layers x 8 coltiles of 32); block 256.
// A band (8 x KK) staged once in LDS [8][APAD]; B chunks [32 cols][KCH]
// staged from row-major CM with register prefetch. Thread = (s k-half,
// r row, c2 col-pair): all LDS reads b128 along k, conflict-free.
// 2-way k-split reduced via 512-float LDS buffer (aliased on Bs).
// ---------------------------------------------------------------------------
__global__ __launch_bounds__(256) void k_stage(const float* __restrict__ rcur,
                                               const float* __restrict__ CM,
                                               const float* __restrict__ cvec,
                                               const float* __restrict__ rc0,
                                               float* __restrict__ rnxt)
{
    __shared__ float As[8 * APAD];
    __shared__ float Bs[32 * BPAD];
    const int bid = blockIdx.x;
    const int t = threadIdx.x;
    const int rowtile = bid >> 5, lc = bid & 31;
    const int l = lc >> 3, d0 = (lc & 7) * 32;
    const int slo = (l == 0) ? 0 : (l - 1);
    const int nj = (l == 0 || l == 3) ? 2 : 3;
    const int KK = nj * 256;
    const int r0 = rowtile * 8;
    const int s = t >> 7, rr_ = (t >> 4) & 7, c2 = t & 15;
    const int bcol = t >> 3, bkq = t & 7;
    const int slotBase = l * 3;
    const int nch = KK >> 6;

    // prefetch B chunk 0 (2 x float4 per thread)
    float4 pb0, pb1;
    {
        const float* p = CM + (size_t)slotBase * DD + (size_t)(d0 + bcol) * 256 + bkq * 8;
        pb0 = *(const float4*)p;
        pb1 = *(const float4*)(p + 4);
    }

    // stage full A band: 8 rows x KK floats
    {
        const float* src = rcur + (size_t)r0 * 1024 + slo * 256;
        const int nf = KK >> 2;
        for (int rr = 0; rr < 8; ++rr)
            for (int c = t; c < nf; c += 256)
                *(float4*)&As[rr * APAD + 4 * c] =
                    *(const float4*)&src[(size_t)rr * 1024 + 4 * c];
    }

    float acc0 = 0.f, acc0b = 0.f, acc1 = 0.f, acc1b = 0.f;
    for (int c = 0; c < nch; ++c) {
        *(float4*)&Bs[bcol * BPAD + bkq * 8] = pb0;
        *(float4*)&Bs[bcol * BPAD + bkq * 8 + 4] = pb1;
        __syncthreads();
        if (c + 1 < nch) {
            const int kg = (c + 1) * KCH;
            const float* p = CM + (size_t)(slotBase + (kg >> 8)) * DD
                           + (size_t)(d0 + bcol) * 256 + (kg & 255) + bkq * 8;
            pb0 = *(const float4*)p;
            pb1 = *(const float4*)(p + 4);
        }
        const float* Ap = &As[rr_ * APAD + c * KCH + s * 32];
        const float* Bp0 = &Bs[(2 * c2) * BPAD + s * 32];
        const float* Bp1 = Bp0 + BPAD;
#pragma unroll
        for (int w = 0; w < 4; ++w) {
            float4 a0  = *(const float4*)&Ap[w * 8];
            float4 a1  = *(const float4*)&Ap[w * 8 + 4];
            float4 b00 = *(const float4*)&Bp0[w * 8];
            float4 b01 = *(const float4*)&Bp0[w * 8 + 4];
            float4 b10 = *(const float4*)&Bp1[w * 8];
            float4 b11 = *(const float4*)&Bp1[w * 8 + 4];
            acc0  += a0.x * b00.x + a0.y * b00.y + a0.z * b00.z + a0.w * b00.w;
            acc0b += a1.x * b01.x + a1.y * b01.y + a1.z * b01.z + a1.w * b01.w;
            acc1  += a0.x * b10.x + a0.y * b10.y + a0.z * b10.z + a0.w * b10.w;
            acc1b += a1.x * b11.x + a1.y * b11.y + a1.z * b11.z + a1.w * b11.w;
        }
        __syncthreads();
    }

    // reduce the 2 k-halves via LDS (Bs no longer needed; 512 floats)
    float* Ps = Bs;
    *(float2*)&Ps[(s * 8 + rr_) * 32 + 2 * c2] = make_float2(acc0 + acc0b, acc1 + acc1b);
    __syncthreads();
    {
        const int r = t >> 5, cc = t & 31;
        float v = Ps[r * 32 + cc] + Ps[(8 + r) * 32 + cc];
        const int dcol = d0 + cc;
        float z = v + cvec[l * 256 + dcol];
        if (l == 0) z += rc0[(size_t)(r0 + r) * 256 + dcol];
        float rold = As[r * APAD + (l - slo) * 256 + dcol];
        rnxt[(size_t)(r0 + r) * 1024 + l * 256 + dcol] = rold + 0.1f * tanhf(z);
    }
}

// ---------------------------------------------------------------------------
// k_heads: per-row head computations (refined, sqk/eqk/sqb/eqb, answerable).
// ---------------------------------------------------------------------------
__global__ __launch_bounds__(256) void k_heads(const float* __restrict__ rA,
    const float* __restrict__ ff,
    const float* __restrict__ KSt, const float* __restrict__ KEt,
    const float* __restrict__ ksb, const float* __restrict__ keb,
    const float* __restrict__ vsk, const float* __restrict__ vse,
    const float* __restrict__ scal,
    const float* __restrict__ W1t, const float* __restrict__ b1,
    const float* __restrict__ w2, const float* __restrict__ b2,
    float* __restrict__ sqk, float* __restrict__ eqk,
    float* __restrict__ sqb, float* __restrict__ eqb,
    float* __restrict__ out)
{
    const int row = blockIdx.x, t = threadIdx.x;
    __shared__ float xs[256];
    __shared__ float red[256];
    __shared__ float hp[256];
    __shared__ float hs[128];
    xs[t] = rA[(size_t)row * 1024 + 768 + t] + ff[(size_t)row * 256 + t];
    __syncthreads();
    {
        float a0 = 0.f, a1 = 0.f, a2 = 0.f, a3 = 0.f;
        float e0 = 0.f, e1 = 0.f, e2 = 0.f, e3 = 0.f;
        const float* KS = KSt + t;
        const float* KE = KEt + t;
#pragma unroll 4
        for (int f = 0; f < 256; f += 4) {
            float4 xv = *(const float4*)&xs[f];
            a0 += KS[(size_t)(f + 0) * 256] * xv.x; a1 += KS[(size_t)(f + 1) * 256] * xv.y;
            a2 += KS[(size_t)(f + 2) * 256] * xv.z; a3 += KS[(size_t)(f + 3) * 256] * xv.w;
            e0 += KE[(size_t)(f + 0) * 256] * xv.x; e1 += KE[(size_t)(f + 1) * 256] * xv.y;
            e2 += KE[(size_t)(f + 2) * 256] * xv.z; e3 += KE[(size_t)(f + 3) * 256] * xv.w;
        }
        sqk[(size_t)row * 256 + t] = a0 + a1 + a2 + a3 + ksb[t];
        eqk[(size_t)row * 256 + t] = e0 + e1 + e2 + e3 + keb[t];
    }
    red[t] = vsk[t] * xs[t];
    __syncthreads();
    for (int s = 128; s > 0; s >>= 1) { if (t < s) red[t] += red[t + s]; __syncthreads(); }
    if (t == 0) sqb[row] = red[0] + scal[0];
    __syncthreads();
    red[t] = vse[t] * xs[t];
    __syncthreads();
    for (int s = 128; s > 0; s >>= 1) { if (t < s) red[t] += red[t + s]; __syncthreads(); }
    if (t == 0) eqb[row] = red[0] + scal[1];
    __syncthreads();
    {
        const int j = t & 127, half = t >> 7;
        float a = 0.f;
        const float* W = W1t + (size_t)half * 128 * 128 + j;
        const float* xh = &xs[half * 128];
#pragma unroll 8
        for (int e = 0; e < 128; ++e) a += W[(size_t)e * 128] * xh[e];
        hp[half * 128 + j] = a;
    }
    __syncthreads();
    if (t < 128) {
        float x = hp[t] + hp[128 + t] + b1[t];
        hs[t] = 0.5f * x * (1.f + erff(x * 0.70710678118654752f));
    }
    __syncthreads();
    if (t < 128) { red[t] = hs[t] * w2[t]; red[128 + t] = hs[t] * w2[128 + t]; }
    __syncthreads();
    for (int s = 64; s > 0; s >>= 1) {
        if (t < s) red[t] += red[t + s];
        else if (t >= 128 && t < 128 + s) red[t] += red[t + s];
        __syncthreads();
    }
    if (t == 0)   out[2 * NB * NS + row * 2 + 0] = red[0] + b2[0];
    if (t == 128) out[2 * NB * NS + row * 2 + 1] = red[128] + b2[1];
}

// ---------------------------------------------------------------------------
// logits gather
// ---------------------------------------------------------------------------
__global__ __launch_bounds__(512) void k_logits(const int* __restrict__ ids,
                                                const float* __restrict__ emb,
                                                const float* __restrict__ pos,
                                                const float* __restrict__ sqk,
                                                const float* __restrict__ eqk,
                                                const float* __restrict__ sqb,
                                                const float* __restrict__ eqb,
                                                float* __restrict__ out) {
    const int bid = blockIdx.x;
    const int b = bid >> 2, q = bid & 3;
    const int t = threadIdx.x;
    __shared__ float sk[ND], ek[ND];
    __shared__ int sid[128];
    if (t < 256) sk[t] = sqk[b * ND + t];
    else ek[t - 256] = eqk[b * ND + t - 256];
    if (t < 128) sid[t] = ids[b * NS + q * 128 + t];
    __syncthreads();
    const int w = t >> 6, lane = t & 63;
    const float4 ks = *(const float4*)&sk[4 * lane];
    const float4 ke = *(const float4*)&ek[4 * lane];
    const float qbs = sqb[b], qbe = eqb[b];
    for (int si = w; si < 128; si += 8) {
        const int s = q * 128 + si;
        const int id = sid[si];
        const float4 e4 = *(const float4*)&emb[(size_t)id * ND + 4 * lane];
        const float4 p4 = *(const float4*)&pos[s * ND + 4 * lane];
        float vx = e4.x + p4.x, vy = e4.y + p4.y, vz = e4.z + p4.z, vw = e4.w + p4.w;
        float ds = vx * ks.x + vy * ks.y + vz * ks.z + vw * ks.w;
        float de = vx * ke.x + vy * ke.y + vz * ke.z + vw * ke.w;
#pragma unroll
        for (int off = 32; off >= 1; off >>= 1) {
            ds += __shfl_xor(ds, off);
            de += __shfl_xor(de, off);
        }
        if (lane == 0) {
            out[b * NS + s] = ds + qbs;
            out[NB * NS + b * NS + s] = de + qbe;
        }
    }
}

// ---------------------------------------------------------------------------
extern "C" void kernel_launch(void* const* d_in, const int* in_sizes, int n_in,
                              void* d_out, int out_size, void* d_ws, size_t ws_size,
                              hipStream_t stream) {
    const int*   ids    = (const int*)d_in[0];
    const float* emb    = (const float*)d_in[1];
    const float* pos    = (const float*)d_in[2];
    const float* init_w = (const float*)d_in[3];
    const float* init_b = (const float*)d_in[4];
    const float* pred_w = (const float*)d_in[5];
    const float* pred_b = (const float*)d_in[6];
    const float* upd_w  = (const float*)d_in[7];
    const float* upd_b  = (const float*)d_in[8];
    const float* sw     = (const float*)d_in[9];
    const float* sb     = (const float*)d_in[10];
    const float* ew     = (const float*)d_in[11];
    const float* eb     = (const float*)d_in[12];
    const float* kw     = (const float*)d_in[13];
    const float* kb     = (const float*)d_in[14];
    const float* w1     = (const float*)d_in[15];
    const float* b1     = (const float*)d_in[16];
    const float* w2     = (const float*)d_in[17];
    const float* b2     = (const float*)d_in[18];
    float* out = (float*)d_out;

    float* ws = (float*)d_ws;
    float* partial = ws;                 ws += 1024 * 256;
    float* rA      = ws;                 ws += 256 * 1024;
    float* rB      = ws;                 ws += 256 * 1024;
    float* ff      = ws;                 ws += 256 * 256;
    float* CM      = ws;                 ws += 12 * DD;
    float* CMI     = ws;                 ws += 4 * DD;
    float* KSt     = ws;                 ws += DD;
    float* KEt     = ws;                 ws += DD;
    float* W1t     = ws;                 ws += 256 * 128;
    float* cvec    = ws;                 ws += 4 * 256;
    float* rc0     = ws;                 ws += 256 * 256;
    float* vsk     = ws;                 ws += 256;
    float* vse     = ws;                 ws += 256;
    float* ksb     = ws;                 ws += 256;
    float* keb     = ws;                 ws += 256;
    float* scal    = ws;                 ws += 8;
    float* sqk     = ws;                 ws += 256 * 256;
    float* eqk     = ws;                 ws += 256 * 256;
    float* sqb     = ws;                 ws += 256;
    float* eqb     = ws;                 ws += 256;

    k_pool1<<<1024, 256, 0, stream>>>(ids, emb, pos, partial);

    k_prep<<<1126, 256, 0, stream>>>(pred_w, pred_b, upd_w, upd_b, init_w,
                                     sw, sb, ew, eb, kw, kb, w1, partial,
                                     CM, CMI, KSt, KEt, W1t,
                                     cvec, rc0, vsk, vse, ksb, keb, scal);

    k_init<<<256, 256, 0, stream>>>(partial, CMI, init_b, rA, ff);

    float* cur = rA;
    float* nxt = rB;
    for (int it = 0; it < NITERS; ++it) {
        k_stage<<<1024, 256, 0, stream>>>(cur, CM, cvec, rc0, nxt);
        float* tmp = cur; cur = nxt; nxt = tmp;
    }
    // NITERS even -> final reps in rA

    k_heads<<<256, 256, 0, stream>>>(rA, ff, KSt, KEt, ksb, keb, vsk, vse, scal,
                                     W1t, b1, w2, b2, sqk, eqk, sqb, eqb, out);

    k_logits<<<1024, 512, 0, stream>>>(ids, emb, pos, sqk, eqk, sqb, eqb, out);
}

// Round 7
// 263.909 us; speedup vs baseline: 3.8986x; 3.8986x over previous
//
#include <hip/hip_runtime.h>
#include <math.h>

#define NB 256
#define NS 512
#define ND 256
#define NL 4
#define NITERS 10
#define DD (ND*ND)      // 65536

// ---------------------------------------------------------------------------
// K1: partial[(4b+q)][d] = sum over 128 s of emb[ids[b,s]][d] + pos[s][d]
// ---------------------------------------------------------------------------
__global__ __launch_bounds__(256) void k_pool1(const int* __restrict__ ids,
                                               const float* __restrict__ emb,
                                               const float* __restrict__ pos,
                                               float* __restrict__ partial) {
    const int bid = blockIdx.x;
    const int b = bid >> 2, q = bid & 3;
    const int t = threadIdx.x;
    __shared__ int sid[128];
    if (t < 128) sid[t] = ids[b * NS + q * 128 + t];
    __syncthreads();
    float acc = 0.f;
#pragma unroll 8
    for (int s = 0; s < 128; ++s)
        acc += emb[(size_t)sid[s] * ND + t] + pos[(q * 128 + s) * ND + t];
    partial[bid * ND + t] = acc;
}

// ---------------------------------------------------------------------------
// k_prep (round-5 verified version): combined matrices stored TRANSPOSED
// [k][d] for coalesced apply.
//   CM slots (each DD floats): 0:G0 1:H0 3:U1t 4:G1 5:H1 6:U2t 7:G2 8:H2
//                              9:U3t 10:G3      (G=0.5U-UP, H=-0.5UP')
//   rc0[row][d] = (U0 . pooled_row)[d]
//   KSt[f][e] = sum_k sw[k][f]*kw[k][e]
// ---------------------------------------------------------------------------
__global__ __launch_bounds__(256) void k_prep(
    const float* __restrict__ pred_w, const float* __restrict__ pred_b,
    const float* __restrict__ upd_w,  const float* __restrict__ upd_b,
    const float* __restrict__ init_w,
    const float* __restrict__ sw, const float* __restrict__ sb,
    const float* __restrict__ ew, const float* __restrict__ eb,
    const float* __restrict__ kw, const float* __restrict__ kb,
    const float* __restrict__ w1,
    const float* __restrict__ partial,
    float* __restrict__ CM, float* __restrict__ CMI,
    float* __restrict__ KSt, float* __restrict__ KEt, float* __restrict__ W1t,
    float* __restrict__ cvec, float* __restrict__ rc0,
    float* __restrict__ vsk, float* __restrict__ vse,
    float* __restrict__ ksb, float* __restrict__ keb, float* __restrict__ scal)
{
    const int bid = blockIdx.x;
    const int t = threadIdx.x;

    if (bid < 576 || (bid >= 1056 && bid < 1120)) {
        // GEMM blocks: OUT[i][j] = alpha*sum_e A(e,i)*B(j|e) + tau*T[j][i]
        int id, tile;
        if (bid < 576) { id = bid >> 6; tile = bid & 63; }
        else           { id = 9;        tile = bid - 1056; }
        const float* Asrc = nullptr; const float* Bsrc = nullptr;
        float alpha = 1.f, tau = 0.f; float* outp = nullptr;
        bool bT = false, aPool = false;
        switch (id) {
            case 0: Asrc = pred_w;        Bsrc = upd_w;        alpha=-1.f;  tau=0.5f; outp = CM + 0*(size_t)DD; break;
            case 1: Asrc = pred_w + DD;   Bsrc = upd_w;        alpha=-0.5f;           outp = CM + 1*(size_t)DD; break;
            case 2: Asrc = pred_w + DD;   Bsrc = upd_w + DD;   alpha=-1.f;  tau=0.5f; outp = CM + 4*(size_t)DD; break;
            case 3: Asrc = pred_w + 2*DD; Bsrc = upd_w + DD;   alpha=-0.5f;           outp = CM + 5*(size_t)DD; break;
            case 4: Asrc = pred_w + 2*DD; Bsrc = upd_w + 2*DD; alpha=-1.f;  tau=0.5f; outp = CM + 7*(size_t)DD; break;
            case 5: Asrc = pred_w + 3*DD; Bsrc = upd_w + 2*DD; alpha=-0.5f;           outp = CM + 8*(size_t)DD; break;
            case 6: Asrc = pred_w + 3*DD; Bsrc = upd_w + 3*DD; alpha=-1.f;            outp = CM + 10*(size_t)DD; break;
            case 7: Asrc = sw; Bsrc = kw; bT = true; outp = KSt; break;
            case 8: Asrc = ew; Bsrc = kw; bT = true; outp = KEt; break;
            default: Bsrc = upd_w; aPool = true; outp = rc0; break; // rc0: A=pooled, B=U0
        }
        const float* Tsrc = (tau != 0.f) ? Bsrc : nullptr;
        const int i0 = (tile >> 3) * 32, j0 = (tile & 7) * 32;
        __shared__ float As[32 * 33];
        __shared__ float Bs[32 * 33];
        const int tx = t & 15, ty = t >> 4;
        float a00 = 0.f, a01 = 0.f, a10 = 0.f, a11 = 0.f;
        for (int e0 = 0; e0 < 256; e0 += 32) {
            __syncthreads();
            if (!aPool) { // T-form: As[e][i] = Asrc[e][i]
                const int ii = t & 31, e8 = t >> 5;
#pragma unroll
                for (int p = 0; p < 4; ++p) {
                    int ee = e8 + 8 * p;
                    As[ee * 33 + ii] = Asrc[(size_t)(e0 + ee) * 256 + i0 + ii];
                }
            } else {      // pooled rows from partial
                const int ee = t & 31, i8 = t >> 5;
#pragma unroll
                for (int p = 0; p < 4; ++p) {
                    int ii = i8 + 8 * p;
                    const float* pp = partial + (size_t)(i0 + ii) * 4 * 256 + e0 + ee;
                    As[ee * 33 + ii] = (pp[0] + pp[256] + pp[512] + pp[768]) * (1.f / 512.f);
                }
            }
            if (!bT) {    // Bs[e][j] = Bsrc[j][e]
                const int ee = t & 31, j8 = t >> 5;
#pragma unroll
                for (int p = 0; p < 4; ++p) {
                    int jj = j8 + 8 * p;
                    Bs[ee * 33 + jj] = Bsrc[(size_t)(j0 + jj) * 256 + e0 + ee];
                }
            } else {      // Bs[e][j] = Bsrc[e][j]
                const int jj = t & 31, e8 = t >> 5;
#pragma unroll
                for (int p = 0; p < 4; ++p) {
                    int ee = e8 + 8 * p;
                    Bs[ee * 33 + jj] = Bsrc[(size_t)(e0 + ee) * 256 + j0 + jj];
                }
            }
            __syncthreads();
#pragma unroll
            for (int e = 0; e < 32; ++e) {
                float va0 = As[e * 33 + 2 * ty], va1 = As[e * 33 + 2 * ty + 1];
                float vb0 = Bs[e * 33 + 2 * tx], vb1 = Bs[e * 33 + 2 * tx + 1];
                a00 += va0 * vb0; a01 += va0 * vb1;
                a10 += va1 * vb0; a11 += va1 * vb1;
            }
        }
        float t00 = 0.f, t01 = 0.f, t10 = 0.f, t11 = 0.f;
        if (Tsrc) {
            t00 = Tsrc[(size_t)(j0 + 2 * tx) * 256 + i0 + 2 * ty];
            t01 = Tsrc[(size_t)(j0 + 2 * tx + 1) * 256 + i0 + 2 * ty];
            t10 = Tsrc[(size_t)(j0 + 2 * tx) * 256 + i0 + 2 * ty + 1];
            t11 = Tsrc[(size_t)(j0 + 2 * tx + 1) * 256 + i0 + 2 * ty + 1];
        }
        outp[(size_t)(i0 + 2 * ty) * 256 + j0 + 2 * tx]         = alpha * a00 + tau * t00;
        outp[(size_t)(i0 + 2 * ty) * 256 + j0 + 2 * tx + 1]     = alpha * a01 + tau * t01;
        outp[(size_t)(i0 + 2 * ty + 1) * 256 + j0 + 2 * tx]     = alpha * a10 + tau * t10;
        outp[(size_t)(i0 + 2 * ty + 1) * 256 + j0 + 2 * tx + 1] = alpha * a11 + tau * t11;
        return;
    }

    if (bid < 1024) {
        // 256x256 transposes: U1,U2,U3 -> CM 3/6/9; IW0-3 -> CMI
        const int tid = bid - 576;
        const int m = tid >> 6, tile = tid & 63;
        const float* src; float* dst;
        if (m < 3) { src = upd_w + (size_t)(m + 1) * DD; dst = CM + (size_t)(3 + 3 * m) * DD; }
        else       { src = init_w + (size_t)(m - 3) * DD; dst = CMI + (size_t)(m - 3) * DD; }
        const int r0 = (tile >> 3) * 32, c0 = (tile & 7) * 32;
        __shared__ float T[32 * 33];
        const int cc = t & 31, r8 = t >> 5;
#pragma unroll
        for (int p = 0; p < 4; ++p) {
            int rr = r8 + 8 * p;
            T[rr * 33 + cc] = src[(size_t)(r0 + rr) * 256 + c0 + cc];
        }
        __syncthreads();
#pragma unroll
        for (int p = 0; p < 4; ++p) {
            int rr = r8 + 8 * p;
            dst[(size_t)(c0 + rr) * 256 + r0 + cc] = T[cc * 33 + rr];
        }
        return;
    }

    if (bid < 1056) {
        // w1 [128][256] -> W1t [256][128]
        const int tile = bid - 1024;
        const int e0 = (tile >> 2) * 32, j0 = (tile & 3) * 32;
        __shared__ float T[32 * 33];
        const int cc = t & 31, r8 = t >> 5;
#pragma unroll
        for (int p = 0; p < 4; ++p) {
            int jj = r8 + 8 * p;
            T[jj * 33 + cc] = w1[(size_t)(j0 + jj) * 256 + e0 + cc];
        }
        __syncthreads();
#pragma unroll
        for (int p = 0; p < 4; ++p) {
            int ee = r8 + 8 * p;
            W1t[(size_t)(e0 + ee) * 128 + j0 + cc] = T[cc * 33 + ee];
        }
        return;
    }

    const int vb = bid - 1120;
    if (vb < 4) { // c_l[d] = ub_l[d] - sum_k U_l[d][k]*(pb_l[k] + 0.5*pb_{l+1}[k])
        const int l = vb;
        __shared__ float v[256];
        v[t] = (l < 3) ? pred_b[l * 256 + t] + 0.5f * pred_b[(l + 1) * 256 + t]
                       : pred_b[3 * 256 + t];
        __syncthreads();
        const float* U = upd_w + (size_t)l * DD + (size_t)t * 256;
        float acc = 0.f;
#pragma unroll 8
        for (int k = 0; k < 256; k += 4) {
            float4 u = *(const float4*)&U[k];
            acc += u.x * v[k] + u.y * v[k + 1] + u.z * v[k + 2] + u.w * v[k + 3];
        }
        cvec[l * 256 + t] = upd_b[l * 256 + t] - acc;
        return;
    }
    {
        const float* W = (vb == 4) ? sw : ew;
        const float* bb = (vb == 4) ? sb : eb;
        float* vout = (vb == 4) ? vsk : vse;
        float* bout = (vb == 4) ? ksb : keb;
        __shared__ float kbv[256], bbv[256], red[256];
        kbv[t] = kb[t]; bbv[t] = bb[t];
        __syncthreads();
        float a1 = 0.f, a2 = 0.f;
#pragma unroll 4
        for (int k = 0; k < 256; ++k) {
            a1 += W[(size_t)k * 256 + t] * kbv[k];
            a2 += kw[(size_t)k * 256 + t] * bbv[k];
        }
        vout[t] = a1; bout[t] = a2;
        red[t] = kbv[t] * bbv[t];
        __syncthreads();
        for (int s = 128; s > 0; s >>= 1) {
            if (t < s) red[t] += red[t + s];
            __syncthreads();
        }
        if (t == 0) scal[vb - 4] = red[0];
        return;
    }
}

// ---------------------------------------------------------------------------
// k_init: per-row init chain using transposed init weights (coalesced).
// ---------------------------------------------------------------------------
__global__ __launch_bounds__(256) void k_init(const float* __restrict__ partial,
                                              const float* __restrict__ CMI,
                                              const float* __restrict__ init_b,
                                              float* __restrict__ rA,
                                              float* __restrict__ ff)
{
    const int row = blockIdx.x, t = threadIdx.x;
    __shared__ float xs[256];
    {
        const float* p = partial + (size_t)row * 4 * 256 + t;
        xs[t] = (p[0] + p[256] + p[512] + p[768]) * (1.f / 512.f);
    }
    float* rrow = rA + (size_t)row * 1024;
    for (int il = 0; il < 4; ++il) {
        __syncthreads();
        const float* M = CMI + (size_t)il * DD + t;
        float a0 = 0.f, a1 = 0.f, a2 = 0.f, a3 = 0.f;
#pragma unroll 8
        for (int k = 0; k < 256; k += 4) {
            float4 xv = *(const float4*)&xs[k];
            a0 += M[(size_t)(k + 0) * 256] * xv.x;
            a1 += M[(size_t)(k + 1) * 256] * xv.y;
            a2 += M[(size_t)(k + 2) * 256] * xv.z;
            a3 += M[(size_t)(k + 3) * 256] * xv.w;
        }
        float vx = tanhf(a0 + a1 + a2 + a3 + init_b[il * 256 + t]);
        __syncthreads();
        xs[t] = vx;
        rrow[il * 256 + t] = vx;
        if (il == 3) ff[(size_t)row * 256 + t] = vx;
    }
}

// ---------------------------------------------------------------------------
// k_stage v4: XCD-sharded, double-buffered, broadcast-A tiled GEMM.
// grid 256 = [xcd 8] x [lc4-pair 2] x [rowtile 16]; 1 block/CU, all resident.
// Each XCD owns 2 fixed 64-col groups -> its CM slice (~0.3MB) stays
// L2-resident across all 10 stages.
// Block tile: 16 rows x 64 cols; thread = (r = t>>4, 4 cols = (t&15)*4).
// A band [16][776] staged once (broadcast-read); B chunks [64 k][68] dbuf,
// ONE barrier per chunk, global prefetch overlapped with compute.
// ---------------------------------------------------------------------------
__global__ __launch_bounds__(256) void k_stage(const float* __restrict__ rcur,
                                               const float* __restrict__ CM,
                                               const float* __restrict__ cvec,
                                               const float* __restrict__ rc0,
                                               float* __restrict__ rnxt)
{
    __shared__ float As[16 * 776];
    __shared__ float Bs[2][64 * 68];
    const int p = blockIdx.x;
    const int xcd = p & 7, slot_ = p >> 3;         // assume XCD = bid % 8
    const int lc4 = xcd * 2 + (slot_ >> 4);        // 16 col-groups of 64
    const int rowtile = slot_ & 15;
    const int l = lc4 >> 2, dbase = (lc4 & 3) * 64;
    const int slo = (l == 0) ? 0 : (l - 1);
    const int nj = (l == 0 || l == 3) ? 2 : 3;
    const int KK = nj * 256;
    const int nch = KK >> 6;
    const int r0 = rowtile * 16;
    const int t = threadIdx.x;
    const int r = t >> 4, cq4 = (t & 15) * 4;
    const int slotBase = l * 3;

    // ---- stage A band: 16 rows x KK floats (bulk, deep MLP) ----
    const int nf = KK >> 2;
    {
        const float* src = rcur + (size_t)r0 * 1024 + slo * 256;
#pragma unroll
        for (int rr = 0; rr < 16; ++rr)
            if (t < nf)
                *(float4*)&As[rr * 776 + 4 * t] =
                    *(const float4*)&src[(size_t)rr * 1024 + 4 * t];
    }

    // ---- prefetch B chunk 0: 4 float4/thread, coalesced along d ----
    const int kk0 = t >> 4;  // 0..15
    float4 pb0, pb1, pb2, pb3;
    {
        const float* base = CM + (size_t)slotBase * DD + dbase + cq4;
        pb0 = *(const float4*)&base[(size_t)(kk0 +  0) * 256];
        pb1 = *(const float4*)&base[(size_t)(kk0 + 16) * 256];
        pb2 = *(const float4*)&base[(size_t)(kk0 + 32) * 256];
        pb3 = *(const float4*)&base[(size_t)(kk0 + 48) * 256];
    }

    float4 acc = make_float4(0.f, 0.f, 0.f, 0.f);
    for (int c = 0; c < nch; ++c) {
        float* B = &Bs[c & 1][0];
        *(float4*)&B[(kk0 +  0) * 68 + cq4] = pb0;
        *(float4*)&B[(kk0 + 16) * 68 + cq4] = pb1;
        *(float4*)&B[(kk0 + 32) * 68 + cq4] = pb2;
        *(float4*)&B[(kk0 + 48) * 68 + cq4] = pb3;
        __syncthreads();                       // one barrier per chunk
        if (c + 1 < nch) {
            const int kg = (c + 1) * 64;
            const float* base = CM + (size_t)(slotBase + (kg >> 8)) * DD
                              + (size_t)(kg & 255) * 256 + dbase + cq4;
            pb0 = *(const float4*)&base[(size_t)(kk0 +  0) * 256];
            pb1 = *(const float4*)&base[(size_t)(kk0 + 16) * 256];
            pb2 = *(const float4*)&base[(size_t)(kk0 + 32) * 256];
            pb3 = *(const float4*)&base[(size_t)(kk0 + 48) * 256];
        }
        const float* Ap = &As[r * 776 + c * 64];
#pragma unroll
        for (int q = 0; q < 16; ++q) {
            float4 a = *(const float4*)&Ap[4 * q];
            const float* bp = &B[(4 * q) * 68 + cq4];
            float4 b0 = *(const float4*)&bp[0];
            float4 b1 = *(const float4*)&bp[68];
            float4 b2 = *(const float4*)&bp[136];
            float4 b3 = *(const float4*)&bp[204];
            acc.x += a.x * b0.x + a.y * b1.x + a.z * b2.x + a.w * b3.x;
            acc.y += a.x * b0.y + a.y * b1.y + a.z * b2.y + a.w * b3.y;
            acc.z += a.x * b0.z + a.y * b1.z + a.z * b2.z + a.w * b3.z;
            acc.w += a.x * b0.w + a.y * b1.w + a.z * b2.w + a.w * b3.w;
        }
    }

    // ---- epilogue: z + cvec (+rc0), r_new = r_old + 0.1*tanh(z) ----
    const int dcol = dbase + cq4;              // within-layer col
    const int grow = r0 + r;
    float4 cv = *(const float4*)&cvec[l * 256 + dcol];
    float z0 = acc.x + cv.x, z1 = acc.y + cv.y;
    float z2 = acc.z + cv.z, z3 = acc.w + cv.w;
    if (l == 0) {
        float4 rc = *(const float4*)&rc0[(size_t)grow * 256 + dcol];
        z0 += rc.x; z1 += rc.y; z2 += rc.z; z3 += rc.w;
    }
    float4 rold = *(const float4*)&As[r * 776 + (l - slo) * 256 + dcol];
    float4 o;
    o.x = rold.x + 0.1f * tanhf(z0);
    o.y = rold.y + 0.1f * tanhf(z1);
    o.z = rold.z + 0.1f * tanhf(z2);
    o.w = rold.w + 0.1f * tanhf(z3);
    *(float4*)&rnxt[(size_t)grow * 1024 + l * 256 + dcol] = o;
}

// ---------------------------------------------------------------------------
// k_heads: per-row head computations (refined, sqk/eqk/sqb/eqb, answerable).
// ---------------------------------------------------------------------------
__global__ __launch_bounds__(256) void k_heads(const float* __restrict__ rA,
    const float* __restrict__ ff,
    const float* __restrict__ KSt, const float* __restrict__ KEt,
    const float* __restrict__ ksb, const float* __restrict__ keb,
    const float* __restrict__ vsk, const float* __restrict__ vse,
    const float* __restrict__ scal,
    const float* __restrict__ W1t, const float* __restrict__ b1,
    const float* __restrict__ w2, const float* __restrict__ b2,
    float* __restrict__ sqk, float* __restrict__ eqk,
    float* __restrict__ sqb, float* __restrict__ eqb,
    float* __restrict__ out)
{
    const int row = blockIdx.x, t = threadIdx.x;
    __shared__ float xs[256];
    __shared__ float red[256];
    __shared__ float hp[256];
    __shared__ float hs[128];
    xs[t] = rA[(size_t)row * 1024 + 768 + t] + ff[(size_t)row * 256 + t];
    __syncthreads();
    {
        float a0 = 0.f, a1 = 0.f, a2 = 0.f, a3 = 0.f;
        float e0 = 0.f, e1 = 0.f, e2 = 0.f, e3 = 0.f;
        const float* KS = KSt + t;
        const float* KE = KEt + t;
#pragma unroll 4
        for (int f = 0; f < 256; f += 4) {
            float4 xv = *(const float4*)&xs[f];
            a0 += KS[(size_t)(f + 0) * 256] * xv.x; a1 += KS[(size_t)(f + 1) * 256] * xv.y;
            a2 += KS[(size_t)(f + 2) * 256] * xv.z; a3 += KS[(size_t)(f + 3) * 256] * xv.w;
            e0 += KE[(size_t)(f + 0) * 256] * xv.x; e1 += KE[(size_t)(f + 1) * 256] * xv.y;
            e2 += KE[(size_t)(f + 2) * 256] * xv.z; e3 += KE[(size_t)(f + 3) * 256] * xv.w;
        }
        sqk[(size_t)row * 256 + t] = a0 + a1 + a2 + a3 + ksb[t];
        eqk[(size_t)row * 256 + t] = e0 + e1 + e2 + e3 + keb[t];
    }
    red[t] = vsk[t] * xs[t];
    __syncthreads();
    for (int s = 128; s > 0; s >>= 1) { if (t < s) red[t] += red[t + s]; __syncthreads(); }
    if (t == 0) sqb[row] = red[0] + scal[0];
    __syncthreads();
    red[t] = vse[t] * xs[t];
    __syncthreads();
    for (int s = 128; s > 0; s >>= 1) { if (t < s) red[t] += red[t + s]; __syncthreads(); }
    if (t == 0) eqb[row] = red[0] + scal[1];
    __syncthreads();
    {
        const int j = t & 127, half = t >> 7;
        float a = 0.f;
        const float* W = W1t + (size_t)half * 128 * 128 + j;
        const float* xh = &xs[half * 128];
#pragma unroll 8
        for (int e = 0; e < 128; ++e) a += W[(size_t)e * 128] * xh[e];
        hp[half * 128 + j] = a;
    }
    __syncthreads();
    if (t < 128) {
        float x = hp[t] + hp[128 + t] + b1[t];
        hs[t] = 0.5f * x * (1.f + erff(x * 0.70710678118654752f));
    }
    __syncthreads();
    if (t < 128) { red[t] = hs[t] * w2[t]; red[128 + t] = hs[t] * w2[128 + t]; }
    __syncthreads();
    for (int s = 64; s > 0; s >>= 1) {
        if (t < s) red[t] += red[t + s];
        else if (t >= 128 && t < 128 + s) red[t] += red[t + s];
        __syncthreads();
    }
    if (t == 0)   out[2 * NB * NS + row * 2 + 0] = red[0] + b2[0];
    if (t == 128) out[2 * NB * NS + row * 2 + 1] = red[128] + b2[1];
}

// ---------------------------------------------------------------------------
// logits gather
// ---------------------------------------------------------------------------
__global__ __launch_bounds__(512) void k_logits(const int* __restrict__ ids,
                                                const float* __restrict__ emb,
                                                const float* __restrict__ pos,
                                                const float* __restrict__ sqk,
                                                const float* __restrict__ eqk,
                                                const float* __restrict__ sqb,
                                                const float* __restrict__ eqb,
                                                float* __restrict__ out) {
    const int bid = blockIdx.x;
    const int b = bid >> 2, q = bid & 3;
    const int t = threadIdx.x;
    __shared__ float sk[ND], ek[ND];
    __shared__ int sid[128];
    if (t < 256) sk[t] = sqk[b * ND + t];
    else ek[t - 256] = eqk[b * ND + t - 256];
    if (t < 128) sid[t] = ids[b * NS + q * 128 + t];
    __syncthreads();
    const int w = t >> 6, lane = t & 63;
    const float4 ks = *(const float4*)&sk[4 * lane];
    const float4 ke = *(const float4*)&ek[4 * lane];
    const float qbs = sqb[b], qbe = eqb[b];
    for (int si = w; si < 128; si += 8) {
        const int s = q * 128 + si;
        const int id = sid[si];
        const float4 e4 = *(const float4*)&emb[(size_t)id * ND + 4 * lane];
        const float4 p4 = *(const float4*)&pos[s * ND + 4 * lane];
        float vx = e4.x + p4.x, vy = e4.y + p4.y, vz = e4.z + p4.z, vw = e4.w + p4.w;
        float ds = vx * ks.x + vy * ks.y + vz * ks.z + vw * ks.w;
        float de = vx * ke.x + vy * ke.y + vz * ke.z + vw * ke.w;
#pragma unroll
        for (int off = 32; off >= 1; off >>= 1) {
            ds += __shfl_xor(ds, off);
            de += __shfl_xor(de, off);
        }
        if (lane == 0) {
            out[b * NS + s] = ds + qbs;
            out[NB * NS + b * NS + s] = de + qbe;
        }
    }
}

// ---------------------------------------------------------------------------
extern "C" void kernel_launch(void* const* d_in, const int* in_sizes, int n_in,
                              void* d_out, int out_size, void* d_ws, size_t ws_size,
                              hipStream_t stream) {
    const int*   ids    = (const int*)d_in[0];
    const float* emb    = (const float*)d_in[1];
    const float* pos    = (const float*)d_in[2];
    const float* init_w = (const float*)d_in[3];
    const float* init_b = (const float*)d_in[4];
    const float* pred_w = (const float*)d_in[5];
    const float* pred_b = (const float*)d_in[6];
    const float* upd_w  = (const float*)d_in[7];
    const float* upd_b  = (const float*)d_in[8];
    const float* sw     = (const float*)d_in[9];
    const float* sb     = (const float*)d_in[10];
    const float* ew     = (const float*)d_in[11];
    const float* eb     = (const float*)d_in[12];
    const float* kw     = (const float*)d_in[13];
    const float* kb     = (const float*)d_in[14];
    const float* w1     = (const float*)d_in[15];
    const float* b1     = (const float*)d_in[16];
    const float* w2     = (const float*)d_in[17];
    const float* b2     = (const float*)d_in[18];
    float* out = (float*)d_out;

    float* ws = (float*)d_ws;
    float* partial = ws;                 ws += 1024 * 256;
    float* rA      = ws;                 ws += 256 * 1024;
    float* rB      = ws;                 ws += 256 * 1024;
    float* ff      = ws;                 ws += 256 * 256;
    float* CM      = ws;                 ws += 12 * DD;
    float* CMI     = ws;                 ws += 4 * DD;
    float* KSt     = ws;                 ws += DD;
    float* KEt     = ws;                 ws += DD;
    float* W1t     = ws;                 ws += 256 * 128;
    float* cvec    = ws;                 ws += 4 * 256;
    float* rc0     = ws;                 ws += 256 * 256;
    float* vsk     = ws;                 ws += 256;
    float* vse     = ws;                 ws += 256;
    float* ksb     = ws;                 ws += 256;
    float* keb     = ws;                 ws += 256;
    float* scal    = ws;                 ws += 8;
    float* sqk     = ws;                 ws += 256 * 256;
    float* eqk     = ws;                 ws += 256 * 256;
    float* sqb     = ws;                 ws += 256;
    float* eqb     = ws;                 ws += 256;

    k_pool1<<<1024, 256, 0, stream>>>(ids, emb, pos, partial);

    k_prep<<<1126, 256, 0, stream>>>(pred_w, pred_b, upd_w, upd_b, init_w,
                                     sw, sb, ew, eb, kw, kb, w1, partial,
                                     CM, CMI, KSt, KEt, W1t,
                                     cvec, rc0, vsk, vse, ksb, keb, scal);

    k_init<<<256, 256, 0, stream>>>(partial, CMI, init_b, rA, ff);

    float* cur = rA;
    float* nxt = rB;
    for (int it = 0; it < NITERS; ++it) {
        k_stage<<<256, 256, 0, stream>>>(cur, CM, cvec, rc0, nxt);
        float* tmp = cur; cur = nxt; nxt = tmp;
    }
    // NITERS even -> final reps in rA

    k_heads<<<256, 256, 0, stream>>>(rA, ff, KSt, KEt, ksb, keb, vsk, vse, scal,
                                     W1t, b1, w2, b2, sqk, eqk, sqb, eqb, out);

    k_logits<<<1024, 512, 0, stream>>>(ids, emb, pos, sqk, eqk, sqb, eqb, out);
}

// Round 8
// 238.100 us; speedup vs baseline: 4.3212x; 1.1084x over previous
//
#include <hip/hip_runtime.h>
#include <math.h>

#define NB 256
#define NS 512
#define ND 256
#define NL 4
#define NITERS 10
#define DD (ND*ND)      // 65536

// ---------------------------------------------------------------------------
// K1: partial[(4b+q)][d] = sum over 128 s of emb[ids[b,s]][d] + pos[s][d]
// ---------------------------------------------------------------------------
__global__ __launch_bounds__(256) void k_pool1(const int* __restrict__ ids,
                                               const float* __restrict__ emb,
                                               const float* __restrict__ pos,
                                               float* __restrict__ partial) {
    const int bid = blockIdx.x;
    const int b = bid >> 2, q = bid & 3;
    const int t = threadIdx.x;
    __shared__ int sid[128];
    if (t < 128) sid[t] = ids[b * NS + q * 128 + t];
    __syncthreads();
    float acc = 0.f;
#pragma unroll 8
    for (int s = 0; s < 128; ++s)
        acc += emb[(size_t)sid[s] * ND + t] + pos[(q * 128 + s) * ND + t];
    partial[bid * ND + t] = acc;
}

// ---------------------------------------------------------------------------
// k_prep (round-7 verified): combined matrices stored TRANSPOSED [k][d].
//   CM slots: 0:G0 1:H0 3:U1t 4:G1 5:H1 6:U2t 7:G2 8:H2 9:U3t 10:G3
//   rc0[row][d] = (U0 . pooled_row)[d];  KSt[f][e] = sum_k sw[k][f]*kw[k][e]
// ---------------------------------------------------------------------------
__global__ __launch_bounds__(256) void k_prep(
    const float* __restrict__ pred_w, const float* __restrict__ pred_b,
    const float* __restrict__ upd_w,  const float* __restrict__ upd_b,
    const float* __restrict__ init_w,
    const float* __restrict__ sw, const float* __restrict__ sb,
    const float* __restrict__ ew, const float* __restrict__ eb,
    const float* __restrict__ kw, const float* __restrict__ kb,
    const float* __restrict__ w1,
    const float* __restrict__ partial,
    float* __restrict__ CM, float* __restrict__ CMI,
    float* __restrict__ KSt, float* __restrict__ KEt, float* __restrict__ W1t,
    float* __restrict__ cvec, float* __restrict__ rc0,
    float* __restrict__ vsk, float* __restrict__ vse,
    float* __restrict__ ksb, float* __restrict__ keb, float* __restrict__ scal)
{
    const int bid = blockIdx.x;
    const int t = threadIdx.x;

    if (bid < 576 || (bid >= 1056 && bid < 1120)) {
        int id, tile;
        if (bid < 576) { id = bid >> 6; tile = bid & 63; }
        else           { id = 9;        tile = bid - 1056; }
        const float* Asrc = nullptr; const float* Bsrc = nullptr;
        float alpha = 1.f, tau = 0.f; float* outp = nullptr;
        bool bT = false, aPool = false;
        switch (id) {
            case 0: Asrc = pred_w;        Bsrc = upd_w;        alpha=-1.f;  tau=0.5f; outp = CM + 0*(size_t)DD; break;
            case 1: Asrc = pred_w + DD;   Bsrc = upd_w;        alpha=-0.5f;           outp = CM + 1*(size_t)DD; break;
            case 2: Asrc = pred_w + DD;   Bsrc = upd_w + DD;   alpha=-1.f;  tau=0.5f; outp = CM + 4*(size_t)DD; break;
            case 3: Asrc = pred_w + 2*DD; Bsrc = upd_w + DD;   alpha=-0.5f;           outp = CM + 5*(size_t)DD; break;
            case 4: Asrc = pred_w + 2*DD; Bsrc = upd_w + 2*DD; alpha=-1.f;  tau=0.5f; outp = CM + 7*(size_t)DD; break;
            case 5: Asrc = pred_w + 3*DD; Bsrc = upd_w + 2*DD; alpha=-0.5f;           outp = CM + 8*(size_t)DD; break;
            case 6: Asrc = pred_w + 3*DD; Bsrc = upd_w + 3*DD; alpha=-1.f;            outp = CM + 10*(size_t)DD; break;
            case 7: Asrc = sw; Bsrc = kw; bT = true; outp = KSt; break;
            case 8: Asrc = ew; Bsrc = kw; bT = true; outp = KEt; break;
            default: Bsrc = upd_w; aPool = true; outp = rc0; break;
        }
        const float* Tsrc = (tau != 0.f) ? Bsrc : nullptr;
        const int i0 = (tile >> 3) * 32, j0 = (tile & 7) * 32;
        __shared__ float As[32 * 33];
        __shared__ float Bs[32 * 33];
        const int tx = t & 15, ty = t >> 4;
        float a00 = 0.f, a01 = 0.f, a10 = 0.f, a11 = 0.f;
        for (int e0 = 0; e0 < 256; e0 += 32) {
            __syncthreads();
            if (!aPool) {
                const int ii = t & 31, e8 = t >> 5;
#pragma unroll
                for (int p = 0; p < 4; ++p) {
                    int ee = e8 + 8 * p;
                    As[ee * 33 + ii] = Asrc[(size_t)(e0 + ee) * 256 + i0 + ii];
                }
            } else {
                const int ee = t & 31, i8 = t >> 5;
#pragma unroll
                for (int p = 0; p < 4; ++p) {
                    int ii = i8 + 8 * p;
                    const float* pp = partial + (size_t)(i0 + ii) * 4 * 256 + e0 + ee;
                    As[ee * 33 + ii] = (pp[0] + pp[256] + pp[512] + pp[768]) * (1.f / 512.f);
                }
            }
            if (!bT) {
                const int ee = t & 31, j8 = t >> 5;
#pragma unroll
                for (int p = 0; p < 4; ++p) {
                    int jj = j8 + 8 * p;
                    Bs[ee * 33 + jj] = Bsrc[(size_t)(j0 + jj) * 256 + e0 + ee];
                }
            } else {
                const int jj = t & 31, e8 = t >> 5;
#pragma unroll
                for (int p = 0; p < 4; ++p) {
                    int ee = e8 + 8 * p;
                    Bs[ee * 33 + jj] = Bsrc[(size_t)(e0 + ee) * 256 + j0 + jj];
                }
            }
            __syncthreads();
#pragma unroll
            for (int e = 0; e < 32; ++e) {
                float va0 = As[e * 33 + 2 * ty], va1 = As[e * 33 + 2 * ty + 1];
                float vb0 = Bs[e * 33 + 2 * tx], vb1 = Bs[e * 33 + 2 * tx + 1];
                a00 += va0 * vb0; a01 += va0 * vb1;
                a10 += va1 * vb0; a11 += va1 * vb1;
            }
        }
        float t00 = 0.f, t01 = 0.f, t10 = 0.f, t11 = 0.f;
        if (Tsrc) {
            t00 = Tsrc[(size_t)(j0 + 2 * tx) * 256 + i0 + 2 * ty];
            t01 = Tsrc[(size_t)(j0 + 2 * tx + 1) * 256 + i0 + 2 * ty];
            t10 = Tsrc[(size_t)(j0 + 2 * tx) * 256 + i0 + 2 * ty + 1];
            t11 = Tsrc[(size_t)(j0 + 2 * tx + 1) * 256 + i0 + 2 * ty + 1];
        }
        outp[(size_t)(i0 + 2 * ty) * 256 + j0 + 2 * tx]         = alpha * a00 + tau * t00;
        outp[(size_t)(i0 + 2 * ty) * 256 + j0 + 2 * tx + 1]     = alpha * a01 + tau * t01;
        outp[(size_t)(i0 + 2 * ty + 1) * 256 + j0 + 2 * tx]     = alpha * a10 + tau * t10;
        outp[(size_t)(i0 + 2 * ty + 1) * 256 + j0 + 2 * tx + 1] = alpha * a11 + tau * t11;
        return;
    }

    if (bid < 1024) {
        const int tid = bid - 576;
        const int m = tid >> 6, tile = tid & 63;
        const float* src; float* dst;
        if (m < 3) { src = upd_w + (size_t)(m + 1) * DD; dst = CM + (size_t)(3 + 3 * m) * DD; }
        else       { src = init_w + (size_t)(m - 3) * DD; dst = CMI + (size_t)(m - 3) * DD; }
        const int r0 = (tile >> 3) * 32, c0 = (tile & 7) * 32;
        __shared__ float T[32 * 33];
        const int cc = t & 31, r8 = t >> 5;
#pragma unroll
        for (int p = 0; p < 4; ++p) {
            int rr = r8 + 8 * p;
            T[rr * 33 + cc] = src[(size_t)(r0 + rr) * 256 + c0 + cc];
        }
        __syncthreads();
#pragma unroll
        for (int p = 0; p < 4; ++p) {
            int rr = r8 + 8 * p;
            dst[(size_t)(c0 + rr) * 256 + r0 + cc] = T[cc * 33 + rr];
        }
        return;
    }

    if (bid < 1056) {
        const int tile = bid - 1024;
        const int e0 = (tile >> 2) * 32, j0 = (tile & 3) * 32;
        __shared__ float T[32 * 33];
        const int cc = t & 31, r8 = t >> 5;
#pragma unroll
        for (int p = 0; p < 4; ++p) {
            int jj = r8 + 8 * p;
            T[jj * 33 + cc] = w1[(size_t)(j0 + jj) * 256 + e0 + cc];
        }
        __syncthreads();
#pragma unroll
        for (int p = 0; p < 4; ++p) {
            int ee = r8 + 8 * p;
            W1t[(size_t)(e0 + ee) * 128 + j0 + cc] = T[cc * 33 + ee];
        }
        return;
    }

    const int vb = bid - 1120;
    if (vb < 4) {
        const int l = vb;
        __shared__ float v[256];
        v[t] = (l < 3) ? pred_b[l * 256 + t] + 0.5f * pred_b[(l + 1) * 256 + t]
                       : pred_b[3 * 256 + t];
        __syncthreads();
        const float* U = upd_w + (size_t)l * DD + (size_t)t * 256;
        float acc = 0.f;
#pragma unroll 8
        for (int k = 0; k < 256; k += 4) {
            float4 u = *(const float4*)&U[k];
            acc += u.x * v[k] + u.y * v[k + 1] + u.z * v[k + 2] + u.w * v[k + 3];
        }
        cvec[l * 256 + t] = upd_b[l * 256 + t] - acc;
        return;
    }
    {
        const float* W = (vb == 4) ? sw : ew;
        const float* bb = (vb == 4) ? sb : eb;
        float* vout = (vb == 4) ? vsk : vse;
        float* bout = (vb == 4) ? ksb : keb;
        __shared__ float kbv[256], bbv[256], red[256];
        kbv[t] = kb[t]; bbv[t] = bb[t];
        __syncthreads();
        float a1 = 0.f, a2 = 0.f;
#pragma unroll 4
        for (int k = 0; k < 256; ++k) {
            a1 += W[(size_t)k * 256 + t] * kbv[k];
            a2 += kw[(size_t)k * 256 + t] * bbv[k];
        }
        vout[t] = a1; bout[t] = a2;
        red[t] = kbv[t] * bbv[t];
        __syncthreads();
        for (int s = 128; s > 0; s >>= 1) {
            if (t < s) red[t] += red[t + s];
            __syncthreads();
        }
        if (t == 0) scal[vb - 4] = red[0];
        return;
    }
}

// ---------------------------------------------------------------------------
// k_init: per-row init chain using transposed init weights (coalesced).
// ---------------------------------------------------------------------------
__global__ __launch_bounds__(256) void k_init(const float* __restrict__ partial,
                                              const float* __restrict__ CMI,
                                              const float* __restrict__ init_b,
                                              float* __restrict__ rA,
                                              float* __restrict__ ff)
{
    const int row = blockIdx.x, t = threadIdx.x;
    __shared__ float xs[256];
    {
        const float* p = partial + (size_t)row * 4 * 256 + t;
        xs[t] = (p[0] + p[256] + p[512] + p[768]) * (1.f / 512.f);
    }
    float* rrow = rA + (size_t)row * 1024;
    for (int il = 0; il < 4; ++il) {
        __syncthreads();
        const float* M = CMI + (size_t)il * DD + t;
        float a0 = 0.f, a1 = 0.f, a2 = 0.f, a3 = 0.f;
#pragma unroll 8
        for (int k = 0; k < 256; k += 4) {
            float4 xv = *(const float4*)&xs[k];
            a0 += M[(size_t)(k + 0) * 256] * xv.x;
            a1 += M[(size_t)(k + 1) * 256] * xv.y;
            a2 += M[(size_t)(k + 2) * 256] * xv.z;
            a3 += M[(size_t)(k + 3) * 256] * xv.w;
        }
        float vx = tanhf(a0 + a1 + a2 + a3 + init_b[il * 256 + t]);
        __syncthreads();
        xs[t] = vx;
        rrow[il * 256 + t] = vx;
        if (il == 3) ff[(size_t)row * 256 + t] = vx;
    }
}

// ---------------------------------------------------------------------------
// k_stage v5: register-tile 8x8 with 32-way k-split.
// grid 256 = 8 rowtiles(32r) x 32 colgroups(32c: l=cg>>3, dbase=(cg&7)*32).
// block 512 thr (8 waves): pos = t&15 -> (pr,pc) 8x8 subtile of 32x32;
// s = t>>4 in [0,32): 4-k slice per 128-k chunk. Per chunk/thread: 16
// ds_read_b128 per 1024 FLOP. XOR-swizzle quad ^= (row>>3)<<2 on both
// tiles (2-way = free). Reduce: shfl over in-wave s, then 35KB LDS scratch.
// ---------------------------------------------------------------------------
__global__ __launch_bounds__(512, 2) void k_stage(const float* __restrict__ rcur,
                                                  const float* __restrict__ CM,
                                                  const float* __restrict__ cvec,
                                                  const float* __restrict__ rc0,
                                                  float* __restrict__ rnxt)
{
    __shared__ float As[32 * 136];
    __shared__ float Bs[32 * 136];
    __shared__ float4 scr[128 * 17];
    const int bid = blockIdx.x;
    const int t = threadIdx.x;
    const int rowtile = bid >> 5, cg = bid & 31;
    const int l = cg >> 3, dbase = (cg & 7) * 32;
    const int slo = (l == 0) ? 0 : (l - 1);
    const int nj = (l == 0 || l == 3) ? 2 : 3;
    const int KK = nj * 256;
    const int nch = KK >> 7;                  // 128-k chunks
    const int r0 = rowtile * 32;
    const int slotBase = l * 3;

    // compute-role indices
    const int pos = t & 15, s = t >> 4;       // s in [0,32)
    const int pr = pos >> 2, pc = pos & 3;
    const int r0t = pr * 8, c0t = pc * 8;
    const int keyA = pr << 2, keyB = pc << 2;
    // staging-role indices
    const int sa_r = t >> 4, sa_f = t & 15;   // A: row, f4-idx (covers sa_f, sa_f+16)
    const int sb_k = t >> 2, sb_d = t & 3;    // B: k-row, d-octet

    float acc[8][8];
#pragma unroll
    for (int i = 0; i < 8; ++i)
#pragma unroll
        for (int j = 0; j < 8; ++j) acc[i][j] = 0.f;

    const float* aSrc = rcur + (size_t)(r0 + sa_r) * 1024 + slo * 256;
    // prefetch chunk 0
    float4 pa0 = *(const float4*)&aSrc[sa_f * 4];
    float4 pa1 = *(const float4*)&aSrc[sa_f * 4 + 64];
    float4 qb0, qb1;
    {
        const float* bp = CM + (size_t)slotBase * DD + (size_t)sb_k * 256 + dbase + sb_d * 8;
        qb0 = *(const float4*)&bp[0];
        qb1 = *(const float4*)&bp[4];
    }

    const int aw0 = sa_r * 136 + 4 * (sa_f ^ ((sa_r >> 3) << 2));
    const int aw1 = sa_r * 136 + 4 * ((sa_f + 16) ^ ((sa_r >> 3) << 2));
    const int kswz = 4 * ((sb_k >> 2) ^ (sb_d << 2)) + (sb_k & 3);
    const int bw0 = (sb_d * 8) * 136 + kswz;

    for (int c = 0; c < nch; ++c) {
        // write staged chunk
        *(float4*)&As[aw0] = pa0;
        *(float4*)&As[aw1] = pa1;
        Bs[bw0 + 0 * 136] = qb0.x; Bs[bw0 + 1 * 136] = qb0.y;
        Bs[bw0 + 2 * 136] = qb0.z; Bs[bw0 + 3 * 136] = qb0.w;
        Bs[bw0 + 4 * 136] = qb1.x; Bs[bw0 + 5 * 136] = qb1.y;
        Bs[bw0 + 6 * 136] = qb1.z; Bs[bw0 + 7 * 136] = qb1.w;
        __syncthreads();
        // prefetch next chunk
        if (c + 1 < nch) {
            const int kg = (c + 1) * 128;
            pa0 = *(const float4*)&aSrc[kg + sa_f * 4];
            pa1 = *(const float4*)&aSrc[kg + sa_f * 4 + 64];
            const float* bp = CM + (size_t)(slotBase + (kg >> 8)) * DD
                            + (size_t)((kg & 255) + sb_k) * 256 + dbase + sb_d * 8;
            qb0 = *(const float4*)&bp[0];
            qb1 = *(const float4*)&bp[4];
        }
        // compute: this thread's 4-k slice
        float4 ar[8], bc[8];
        const int ka = 4 * (s ^ keyA), kb = 4 * (s ^ keyB);
#pragma unroll
        for (int rr = 0; rr < 8; ++rr)
            ar[rr] = *(const float4*)&As[(r0t + rr) * 136 + ka];
#pragma unroll
        for (int cc = 0; cc < 8; ++cc)
            bc[cc] = *(const float4*)&Bs[(c0t + cc) * 136 + kb];
#pragma unroll
        for (int rr = 0; rr < 8; ++rr)
#pragma unroll
            for (int cc = 0; cc < 8; ++cc)
                acc[rr][cc] += ar[rr].x * bc[cc].x + ar[rr].y * bc[cc].y
                             + ar[rr].z * bc[cc].z + ar[rr].w * bc[cc].w;
        __syncthreads();
    }

    // in-wave reduce over the wave's 4 k-slices (lane xor 16, 32)
#pragma unroll
    for (int rr = 0; rr < 8; ++rr)
#pragma unroll
        for (int cc = 0; cc < 8; ++cc) {
            float v = acc[rr][cc];
            v += __shfl_xor(v, 16);
            v += __shfl_xor(v, 32);
            acc[rr][cc] = v;
        }
    const int wave = t >> 6, lane = t & 63;
    if (lane < 16) {
#pragma unroll
        for (int rr = 0; rr < 8; ++rr) {
            scr[(wave * 16 + lane) * 17 + rr * 2 + 0] =
                make_float4(acc[rr][0], acc[rr][1], acc[rr][2], acc[rr][3]);
            scr[(wave * 16 + lane) * 17 + rr * 2 + 1] =
                make_float4(acc[rr][4], acc[rr][5], acc[rr][6], acc[rr][7]);
        }
    }
    __syncthreads();
    // final gather + epilogue: 256 threads, one float4 of outputs each
    if (t < 256) {
        const int rf = t >> 3, cq = t & 7;
        const int pos2 = (rf >> 3) * 4 + (cq >> 1);
        const int idx = pos2 * 17 + (rf & 7) * 2 + (cq & 1);
        float4 sum = scr[idx];
#pragma unroll
        for (int w = 1; w < 8; ++w) {
            float4 v = scr[w * 16 * 17 + idx];
            sum.x += v.x; sum.y += v.y; sum.z += v.z; sum.w += v.w;
        }
        const int dcol = dbase + cq * 4;
        const int grow = r0 + rf;
        float4 cv = *(const float4*)&cvec[l * 256 + dcol];
        float z0 = sum.x + cv.x, z1 = sum.y + cv.y;
        float z2 = sum.z + cv.z, z3 = sum.w + cv.w;
        if (l == 0) {
            float4 rc = *(const float4*)&rc0[(size_t)grow * 256 + dcol];
            z0 += rc.x; z1 += rc.y; z2 += rc.z; z3 += rc.w;
        }
        float4 rold = *(const float4*)&rcur[(size_t)grow * 1024 + l * 256 + dcol];
        float4 o;
        o.x = rold.x + 0.1f * tanhf(z0);
        o.y = rold.y + 0.1f * tanhf(z1);
        o.z = rold.z + 0.1f * tanhf(z2);
        o.w = rold.w + 0.1f * tanhf(z3);
        *(float4*)&rnxt[(size_t)grow * 1024 + l * 256 + dcol] = o;
    }
}

// ---------------------------------------------------------------------------
// k_heads: per-row head computations (refined, sqk/eqk/sqb/eqb, answerable).
// ---------------------------------------------------------------------------
__global__ __launch_bounds__(256) void k_heads(const float* __restrict__ rA,
    const float* __restrict__ ff,
    const float* __restrict__ KSt, const float* __restrict__ KEt,
    const float* __restrict__ ksb, const float* __restrict__ keb,
    const float* __restrict__ vsk, const float* __restrict__ vse,
    const float* __restrict__ scal,
    const float* __restrict__ W1t, const float* __restrict__ b1,
    const float* __restrict__ w2, const float* __restrict__ b2,
    float* __restrict__ sqk, float* __restrict__ eqk,
    float* __restrict__ sqb, float* __restrict__ eqb,
    float* __restrict__ out)
{
    const int row = blockIdx.x, t = threadIdx.x;
    __shared__ float xs[256];
    __shared__ float red[256];
    __shared__ float hp[256];
    __shared__ float hs[128];
    xs[t] = rA[(size_t)row * 1024 + 768 + t] + ff[(size_t)row * 256 + t];
    __syncthreads();
    {
        float a0 = 0.f, a1 = 0.f, a2 = 0.f, a3 = 0.f;
        float e0 = 0.f, e1 = 0.f, e2 = 0.f, e3 = 0.f;
        const float* KS = KSt + t;
        const float* KE = KEt + t;
#pragma unroll 4
        for (int f = 0; f < 256; f += 4) {
            float4 xv = *(const float4*)&xs[f];
            a0 += KS[(size_t)(f + 0) * 256] * xv.x; a1 += KS[(size_t)(f + 1) * 256] * xv.y;
            a2 += KS[(size_t)(f + 2) * 256] * xv.z; a3 += KS[(size_t)(f + 3) * 256] * xv.w;
            e0 += KE[(size_t)(f + 0) * 256] * xv.x; e1 += KE[(size_t)(f + 1) * 256] * xv.y;
            e2 += KE[(size_t)(f + 2) * 256] * xv.z; e3 += KE[(size_t)(f + 3) * 256] * xv.w;
        }
        sqk[(size_t)row * 256 + t] = a0 + a1 + a2 + a3 + ksb[t];
        eqk[(size_t)row * 256 + t] = e0 + e1 + e2 + e3 + keb[t];
    }
    red[t] = vsk[t] * xs[t];
    __syncthreads();
    for (int s = 128; s > 0; s >>= 1) { if (t < s) red[t] += red[t + s]; __syncthreads(); }
    if (t == 0) sqb[row] = red[0] + scal[0];
    __syncthreads();
    red[t] = vse[t] * xs[t];
    __syncthreads();
    for (int s = 128; s > 0; s >>= 1) { if (t < s) red[t] += red[t + s]; __syncthreads(); }
    if (t == 0) eqb[row] = red[0] + scal[1];
    __syncthreads();
    {
        const int j = t & 127, half = t >> 7;
        float a = 0.f;
        const float* W = W1t + (size_t)half * 128 * 128 + j;
        const float* xh = &xs[half * 128];
#pragma unroll 8
        for (int e = 0; e < 128; ++e) a += W[(size_t)e * 128] * xh[e];
        hp[half * 128 + j] = a;
    }
    __syncthreads();
    if (t < 128) {
        float x = hp[t] + hp[128 + t] + b1[t];
        hs[t] = 0.5f * x * (1.f + erff(x * 0.70710678118654752f));
    }
    __syncthreads();
    if (t < 128) { red[t] = hs[t] * w2[t]; red[128 + t] = hs[t] * w2[128 + t]; }
    __syncthreads();
    for (int s = 64; s > 0; s >>= 1) {
        if (t < s) red[t] += red[t + s];
        else if (t >= 128 && t < 128 + s) red[t] += red[t + s];
        __syncthreads();
    }
    if (t == 0)   out[2 * NB * NS + row * 2 + 0] = red[0] + b2[0];
    if (t == 128) out[2 * NB * NS + row * 2 + 1] = red[128] + b2[1];
}

// ---------------------------------------------------------------------------
// logits gather
// ---------------------------------------------------------------------------
__global__ __launch_bounds__(512) void k_logits(const int* __restrict__ ids,
                                                const float* __restrict__ emb,
                                                const float* __restrict__ pos,
                                                const float* __restrict__ sqk,
                                                const float* __restrict__ eqk,
                                                const float* __restrict__ sqb,
                                                const float* __restrict__ eqb,
                                                float* __restrict__ out) {
    const int bid = blockIdx.x;
    const int b = bid >> 2, q = bid & 3;
    const int t = threadIdx.x;
    __shared__ float sk[ND], ek[ND];
    __shared__ int sid[128];
    if (t < 256) sk[t] = sqk[b * ND + t];
    else ek[t - 256] = eqk[b * ND + t - 256];
    if (t < 128) sid[t] = ids[b * NS + q * 128 + t];
    __syncthreads();
    const int w = t >> 6, lane = t & 63;
    const float4 ks = *(const float4*)&sk[4 * lane];
    const float4 ke = *(const float4*)&ek[4 * lane];
    const float qbs = sqb[b], qbe = eqb[b];
    for (int si = w; si < 128; si += 8) {
        const int s = q * 128 + si;
        const int id = sid[si];
        const float4 e4 = *(const float4*)&emb[(size_t)id * ND + 4 * lane];
        const float4 p4 = *(const float4*)&pos[s * ND + 4 * lane];
        float vx = e4.x + p4.x, vy = e4.y + p4.y, vz = e4.z + p4.z, vw = e4.w + p4.w;
        float ds = vx * ks.x + vy * ks.y + vz * ks.z + vw * ks.w;
        float de = vx * ke.x + vy * ke.y + vz * ke.z + vw * ke.w;
#pragma unroll
        for (int off = 32; off >= 1; off >>= 1) {
            ds += __shfl_xor(ds, off);
            de += __shfl_xor(de, off);
        }
        if (lane == 0) {
            out[b * NS + s] = ds + qbs;
            out[NB * NS + b * NS + s] = de + qbe;
        }
    }
}

// ---------------------------------------------------------------------------
extern "C" void kernel_launch(void* const* d_in, const int* in_sizes, int n_in,
                              void* d_out, int out_size, void* d_ws, size_t ws_size,
                              hipStream_t stream) {
    const int*   ids    = (const int*)d_in[0];
    const float* emb    = (const float*)d_in[1];
    const float* pos    = (const float*)d_in[2];
    const float* init_w = (const float*)d_in[3];
    const float* init_b = (const float*)d_in[4];
    const float* pred_w = (const float*)d_in[5];
    const float* pred_b = (const float*)d_in[6];
    const float* upd_w  = (const float*)d_in[7];
    const float* upd_b  = (const float*)d_in[8];
    const float* sw     = (const float*)d_in[9];
    const float* sb     = (const float*)d_in[10];
    const float* ew     = (const float*)d_in[11];
    const float* eb     = (const float*)d_in[12];
    const float* kw     = (const float*)d_in[13];
    const float* kb     = (const float*)d_in[14];
    const float* w1     = (const float*)d_in[15];
    const float* b1     = (const float*)d_in[16];
    const float* w2     = (const float*)d_in[17];
    const float* b2     = (const float*)d_in[18];
    float* out = (float*)d_out;

    float* ws = (float*)d_ws;
    float* partial = ws;                 ws += 1024 * 256;
    float* rA      = ws;                 ws += 256 * 1024;
    float* rB      = ws;                 ws += 256 * 1024;
    float* ff      = ws;                 ws += 256 * 256;
    float* CM      = ws;                 ws += 12 * DD;
    float* CMI     = ws;                 ws += 4 * DD;
    float* KSt     = ws;                 ws += DD;
    float* KEt     = ws;                 ws += DD;
    float* W1t     = ws;                 ws += 256 * 128;
    float* cvec    = ws;                 ws += 4 * 256;
    float* rc0     = ws;                 ws += 256 * 256;
    float* vsk     = ws;                 ws += 256;
    float* vse     = ws;                 ws += 256;
    float* ksb     = ws;                 ws += 256;
    float* keb     = ws;                 ws += 256;
    float* scal    = ws;                 ws += 8;
    float* sqk     = ws;                 ws += 256 * 256;
    float* eqk     = ws;                 ws += 256 * 256;
    float* sqb     = ws;                 ws += 256;
    float* eqb     = ws;                 ws += 256;

    k_pool1<<<1024, 256, 0, stream>>>(ids, emb, pos, partial);

    k_prep<<<1126, 256, 0, stream>>>(pred_w, pred_b, upd_w, upd_b, init_w,
                                     sw, sb, ew, eb, kw, kb, w1, partial,
                                     CM, CMI, KSt, KEt, W1t,
                                     cvec, rc0, vsk, vse, ksb, keb, scal);

    k_init<<<256, 256, 0, stream>>>(partial, CMI, init_b, rA, ff);

    float* cur = rA;
    float* nxt = rB;
    for (int it = 0; it < NITERS; ++it) {
        k_stage<<<256, 512, 0, stream>>>(cur, CM, cvec, rc0, nxt);
        float* tmp = cur; cur = nxt; nxt = tmp;
    }
    // NITERS even -> final reps in rA

    k_heads<<<256, 256, 0, stream>>>(rA, ff, KSt, KEt, ksb, keb, vsk, vse, scal,
                                     W1t, b1, w2, b2, sqk, eqk, sqb, eqb, out);

    k_logits<<<1024, 512, 0, stream>>>(ids, emb, pos, sqk, eqk, sqb, eqb, out);
}

// Round 9
// 233.044 us; speedup vs baseline: 4.4149x; 1.0217x over previous
//
#include <hip/hip_runtime.h>
#include <math.h>

#define NB 256
#define NS 512
#define ND 256
#define NL 4
#define NITERS 10
#define DD (ND*ND)      // 65536
#define BSTR 780        // Bs col stride (float): mult of 4; 780%32=12 -> col bank spread
#define ASTR 132        // As row stride (float)

// ---------------------------------------------------------------------------
// K1: partial[(4b+q)][d] = sum over 128 s of emb[ids[b,s]][d] + pos[s][d]
// ---------------------------------------------------------------------------
__global__ __launch_bounds__(256) void k_pool1(const int* __restrict__ ids,
                                               const float* __restrict__ emb,
                                               const float* __restrict__ pos,
                                               float* __restrict__ partial) {
    const int bid = blockIdx.x;
    const int b = bid >> 2, q = bid & 3;
    const int t = threadIdx.x;
    __shared__ int sid[128];
    if (t < 128) sid[t] = ids[b * NS + q * 128 + t];
    __syncthreads();
    float acc = 0.f;
#pragma unroll 8
    for (int s = 0; s < 128; ++s)
        acc += emb[(size_t)sid[s] * ND + t] + pos[(q * 128 + s) * ND + t];
    partial[bid * ND + t] = acc;
}

// ---------------------------------------------------------------------------
// k_prep (verified rounds 5-8): combined matrices stored TRANSPOSED [k][d].
//   CM slots: 0:G0 1:H0 3:U1t 4:G1 5:H1 6:U2t 7:G2 8:H2 9:U3t 10:G3
//   rc0[row][d] = (U0 . pooled_row)[d];  KSt[f][e] = sum_k sw[k][f]*kw[k][e]
// ---------------------------------------------------------------------------
__global__ __launch_bounds__(256) void k_prep(
    const float* __restrict__ pred_w, const float* __restrict__ pred_b,
    const float* __restrict__ upd_w,  const float* __restrict__ upd_b,
    const float* __restrict__ init_w,
    const float* __restrict__ sw, const float* __restrict__ sb,
    const float* __restrict__ ew, const float* __restrict__ eb,
    const float* __restrict__ kw, const float* __restrict__ kb,
    const float* __restrict__ w1,
    const float* __restrict__ partial,
    float* __restrict__ CM, float* __restrict__ CMI,
    float* __restrict__ KSt, float* __restrict__ KEt, float* __restrict__ W1t,
    float* __restrict__ cvec, float* __restrict__ rc0,
    float* __restrict__ vsk, float* __restrict__ vse,
    float* __restrict__ ksb, float* __restrict__ keb, float* __restrict__ scal)
{
    const int bid = blockIdx.x;
    const int t = threadIdx.x;

    if (bid < 576 || (bid >= 1056 && bid < 1120)) {
        int id, tile;
        if (bid < 576) { id = bid >> 6; tile = bid & 63; }
        else           { id = 9;        tile = bid - 1056; }
        const float* Asrc = nullptr; const float* Bsrc = nullptr;
        float alpha = 1.f, tau = 0.f; float* outp = nullptr;
        bool bT = false, aPool = false;
        switch (id) {
            case 0: Asrc = pred_w;        Bsrc = upd_w;        alpha=-1.f;  tau=0.5f; outp = CM + 0*(size_t)DD; break;
            case 1: Asrc = pred_w + DD;   Bsrc = upd_w;        alpha=-0.5f;           outp = CM + 1*(size_t)DD; break;
            case 2: Asrc = pred_w + DD;   Bsrc = upd_w + DD;   alpha=-1.f;  tau=0.5f; outp = CM + 4*(size_t)DD; break;
            case 3: Asrc = pred_w + 2*DD; Bsrc = upd_w + DD;   alpha=-0.5f;           outp = CM + 5*(size_t)DD; break;
            case 4: Asrc = pred_w + 2*DD; Bsrc = upd_w + 2*DD; alpha=-1.f;  tau=0.5f; outp = CM + 7*(size_t)DD; break;
            case 5: Asrc = pred_w + 3*DD; Bsrc = upd_w + 2*DD; alpha=-0.5f;           outp = CM + 8*(size_t)DD; break;
            case 6: Asrc = pred_w + 3*DD; Bsrc = upd_w + 3*DD; alpha=-1.f;            outp = CM + 10*(size_t)DD; break;
            case 7: Asrc = sw; Bsrc = kw; bT = true; outp = KSt; break;
            case 8: Asrc = ew; Bsrc = kw; bT = true; outp = KEt; break;
            default: Bsrc = upd_w; aPool = true; outp = rc0; break;
        }
        const float* Tsrc = (tau != 0.f) ? Bsrc : nullptr;
        const int i0 = (tile >> 3) * 32, j0 = (tile & 7) * 32;
        __shared__ float As[32 * 33];
        __shared__ float Bs[32 * 33];
        const int tx = t & 15, ty = t >> 4;
        float a00 = 0.f, a01 = 0.f, a10 = 0.f, a11 = 0.f;
        for (int e0 = 0; e0 < 256; e0 += 32) {
            __syncthreads();
            if (!aPool) {
                const int ii = t & 31, e8 = t >> 5;
#pragma unroll
                for (int p = 0; p < 4; ++p) {
                    int ee = e8 + 8 * p;
                    As[ee * 33 + ii] = Asrc[(size_t)(e0 + ee) * 256 + i0 + ii];
                }
            } else {
                const int ee = t & 31, i8 = t >> 5;
#pragma unroll
                for (int p = 0; p < 4; ++p) {
                    int ii = i8 + 8 * p;
                    const float* pp = partial + (size_t)(i0 + ii) * 4 * 256 + e0 + ee;
                    As[ee * 33 + ii] = (pp[0] + pp[256] + pp[512] + pp[768]) * (1.f / 512.f);
                }
            }
            if (!bT) {
                const int ee = t & 31, j8 = t >> 5;
#pragma unroll
                for (int p = 0; p < 4; ++p) {
                    int jj = j8 + 8 * p;
                    Bs[ee * 33 + jj] = Bsrc[(size_t)(j0 + jj) * 256 + e0 + ee];
                }
            } else {
                const int jj = t & 31, e8 = t >> 5;
#pragma unroll
                for (int p = 0; p < 4; ++p) {
                    int ee = e8 + 8 * p;
                    Bs[ee * 33 + jj] = Bsrc[(size_t)(e0 + ee) * 256 + j0 + jj];
                }
            }
            __syncthreads();
#pragma unroll
            for (int e = 0; e < 32; ++e) {
                float va0 = As[e * 33 + 2 * ty], va1 = As[e * 33 + 2 * ty + 1];
                float vb0 = Bs[e * 33 + 2 * tx], vb1 = Bs[e * 33 + 2 * tx + 1];
                a00 += va0 * vb0; a01 += va0 * vb1;
                a10 += va1 * vb0; a11 += va1 * vb1;
            }
        }
        float t00 = 0.f, t01 = 0.f, t10 = 0.f, t11 = 0.f;
        if (Tsrc) {
            t00 = Tsrc[(size_t)(j0 + 2 * tx) * 256 + i0 + 2 * ty];
            t01 = Tsrc[(size_t)(j0 + 2 * tx + 1) * 256 + i0 + 2 * ty];
            t10 = Tsrc[(size_t)(j0 + 2 * tx) * 256 + i0 + 2 * ty + 1];
            t11 = Tsrc[(size_t)(j0 + 2 * tx + 1) * 256 + i0 + 2 * ty + 1];
        }
        outp[(size_t)(i0 + 2 * ty) * 256 + j0 + 2 * tx]         = alpha * a00 + tau * t00;
        outp[(size_t)(i0 + 2 * ty) * 256 + j0 + 2 * tx + 1]     = alpha * a01 + tau * t01;
        outp[(size_t)(i0 + 2 * ty + 1) * 256 + j0 + 2 * tx]     = alpha * a10 + tau * t10;
        outp[(size_t)(i0 + 2 * ty + 1) * 256 + j0 + 2 * tx + 1] = alpha * a11 + tau * t11;
        return;
    }

    if (bid < 1024) {
        const int tid = bid - 576;
        const int m = tid >> 6, tile = tid & 63;
        const float* src; float* dst;
        if (m < 3) { src = upd_w + (size_t)(m + 1) * DD; dst = CM + (size_t)(3 + 3 * m) * DD; }
        else       { src = init_w + (size_t)(m - 3) * DD; dst = CMI + (size_t)(m - 3) * DD; }
        const int r0 = (tile >> 3) * 32, c0 = (tile & 7) * 32;
        __shared__ float T[32 * 33];
        const int cc = t & 31, r8 = t >> 5;
#pragma unroll
        for (int p = 0; p < 4; ++p) {
            int rr = r8 + 8 * p;
            T[rr * 33 + cc] = src[(size_t)(r0 + rr) * 256 + c0 + cc];
        }
        __syncthreads();
#pragma unroll
        for (int p = 0; p < 4; ++p) {
            int rr = r8 + 8 * p;
            dst[(size_t)(c0 + rr) * 256 + r0 + cc] = T[cc * 33 + rr];
        }
        return;
    }

    if (bid < 1056) {
        const int tile = bid - 1024;
        const int e0 = (tile >> 2) * 32, j0 = (tile & 3) * 32;
        __shared__ float T[32 * 33];
        const int cc = t & 31, r8 = t >> 5;
#pragma unroll
        for (int p = 0; p < 4; ++p) {
            int jj = r8 + 8 * p;
            T[jj * 33 + cc] = w1[(size_t)(j0 + jj) * 256 + e0 + cc];
        }
        __syncthreads();
#pragma unroll
        for (int p = 0; p < 4; ++p) {
            int ee = r8 + 8 * p;
            W1t[(size_t)(e0 + ee) * 128 + j0 + cc] = T[cc * 33 + ee];
        }
        return;
    }

    const int vb = bid - 1120;
    if (vb < 4) {
        const int l = vb;
        __shared__ float v[256];
        v[t] = (l < 3) ? pred_b[l * 256 + t] + 0.5f * pred_b[(l + 1) * 256 + t]
                       : pred_b[3 * 256 + t];
        __syncthreads();
        const float* U = upd_w + (size_t)l * DD + (size_t)t * 256;
        float acc = 0.f;
#pragma unroll 8
        for (int k = 0; k < 256; k += 4) {
            float4 u = *(const float4*)&U[k];
            acc += u.x * v[k] + u.y * v[k + 1] + u.z * v[k + 2] + u.w * v[k + 3];
        }
        cvec[l * 256 + t] = upd_b[l * 256 + t] - acc;
        return;
    }
    {
        const float* W = (vb == 4) ? sw : ew;
        const float* bb = (vb == 4) ? sb : eb;
        float* vout = (vb == 4) ? vsk : vse;
        float* bout = (vb == 4) ? ksb : keb;
        __shared__ float kbv[256], bbv[256], red[256];
        kbv[t] = kb[t]; bbv[t] = bb[t];
        __syncthreads();
        float a1 = 0.f, a2 = 0.f;
#pragma unroll 4
        for (int k = 0; k < 256; ++k) {
            a1 += W[(size_t)k * 256 + t] * kbv[k];
            a2 += kw[(size_t)k * 256 + t] * bbv[k];
        }
        vout[t] = a1; bout[t] = a2;
        red[t] = kbv[t] * bbv[t];
        __syncthreads();
        for (int s = 128; s > 0; s >>= 1) {
            if (t < s) red[t] += red[t + s];
            __syncthreads();
        }
        if (t == 0) scal[vb - 4] = red[0];
        return;
    }
}

// ---------------------------------------------------------------------------
// k_init: per-row init chain using transposed init weights (coalesced).
// ---------------------------------------------------------------------------
__global__ __launch_bounds__(256) void k_init(const float* __restrict__ partial,
                                              const float* __restrict__ CMI,
                                              const float* __restrict__ init_b,
                                              float* __restrict__ rA,
                                              float* __restrict__ ff)
{
    const int row = blockIdx.x, t = threadIdx.x;
    __shared__ float xs[256];
    {
        const float* p = partial + (size_t)row * 4 * 256 + t;
        xs[t] = (p[0] + p[256] + p[512] + p[768]) * (1.f / 512.f);
    }
    float* rrow = rA + (size_t)row * 1024;
    for (int il = 0; il < 4; ++il) {
        __syncthreads();
        const float* M = CMI + (size_t)il * DD + t;
        float a0 = 0.f, a1 = 0.f, a2 = 0.f, a3 = 0.f;
#pragma unroll 8
        for (int k = 0; k < 256; k += 4) {
            float4 xv = *(const float4*)&xs[k];
            a0 += M[(size_t)(k + 0) * 256] * xv.x;
            a1 += M[(size_t)(k + 1) * 256] * xv.y;
            a2 += M[(size_t)(k + 2) * 256] * xv.z;
            a3 += M[(size_t)(k + 3) * 256] * xv.w;
        }
        float vx = tanhf(a0 + a1 + a2 + a3 + init_b[il * 256 + t]);
        __syncthreads();
        xs[t] = vx;
        rrow[il * 256 + t] = vx;
        if (il == 3) ff[(size_t)row * 256 + t] = vx;
    }
}

// ---------------------------------------------------------------------------
// k_stage v6: barrier-free main loop.
// grid 256 = 8 rowtiles(32r) x 32 cgs (l=cg>>3, dbase=(cg&7)*32); block 256.
// B (CM slice [32 cols][KK]) staged ONCE into 99.8KB LDS -> ONE barrier.
// Each wave owns 8 rows; A chunks (8x128k) go global->wave-private LDS
// (in-wave lgkmcnt ordering, no barriers), 1-chunk register prefetch.
// Thread: 8r x 8c x 4k slice (16-way in-wave k-split).
// Reduce: 2 shfl_xor rounds + wave-private LDS exchange (reuses A region).
// ---------------------------------------------------------------------------
__global__ __launch_bounds__(256) void k_stage(const float* __restrict__ rcur,
                                               const float* __restrict__ CM,
                                               const float* __restrict__ cvec,
                                               const float* __restrict__ rc0,
                                               float* __restrict__ rnxt)
{
    __shared__ float Bs[32 * BSTR];        // 99.8 KB
    __shared__ float As[4 * 8 * ASTR];     // 16.9 KB (also reduce scratch)
    const int bid = blockIdx.x;
    const int t = threadIdx.x;
    const int rowtile = bid >> 5, cg = bid & 31;
    const int l = cg >> 3, dbase = (cg & 7) * 32;
    const int slo = (l == 0) ? 0 : (l - 1);
    const int nj = (l == 0 || l == 3) ? 2 : 3;
    const int KK = nj * 256;
    const int nch = KK >> 7;               // 128-k chunks: 4 or 6
    const int r0 = rowtile * 32;
    const int slotBase = l * 3;

    // ---- stage B persistent: Bs[col][k] ----
    {
        const int col4 = (t & 7) * 4, k32 = t >> 3;     // k32 in [0,32)
        const float* src = CM + (size_t)slotBase * DD + dbase + col4;
        for (int k = k32; k < KK; k += 32) {
            float4 v = *(const float4*)&src[(size_t)k * 256];
            Bs[(col4 + 0) * BSTR + k] = v.x;
            Bs[(col4 + 1) * BSTR + k] = v.y;
            Bs[(col4 + 2) * BSTR + k] = v.z;
            Bs[(col4 + 3) * BSTR + k] = v.w;
        }
    }
    __syncthreads();   // the ONLY block barrier

    const int wv = t >> 6, lane = t & 63;
    const int arow = lane >> 3, af = lane & 7;     // A-staging role
    const int cpair = lane & 3, ks = lane >> 2;    // compute role: ks in [0,16)
    float* Aw = As + wv * (8 * ASTR);

    float acc[8][8];
#pragma unroll
    for (int i = 0; i < 8; ++i)
#pragma unroll
        for (int j = 0; j < 8; ++j) acc[i][j] = 0.f;

    const float* aSrc = rcur + (size_t)(r0 + wv * 8 + arow) * 1024 + slo * 256;

    // prefetch chunk 0 (4 x float4 = this lane's 64B of the 8x128k chunk)
    float4 pa0 = *(const float4*)&aSrc[af * 4];
    float4 pa1 = *(const float4*)&aSrc[af * 4 + 32];
    float4 pa2 = *(const float4*)&aSrc[af * 4 + 64];
    float4 pa3 = *(const float4*)&aSrc[af * 4 + 96];

    for (int c = 0; c < nch; ++c) {
        // write staged A chunk (wave-private region; lgkmcnt orders w->r)
        *(float4*)&Aw[arow * ASTR + af * 4]      = pa0;
        *(float4*)&Aw[arow * ASTR + af * 4 + 32] = pa1;
        *(float4*)&Aw[arow * ASTR + af * 4 + 64] = pa2;
        *(float4*)&Aw[arow * ASTR + af * 4 + 96] = pa3;
        // prefetch next chunk
        if (c + 1 < nch) {
            const int kg = (c + 1) * 128;
            pa0 = *(const float4*)&aSrc[kg + af * 4];
            pa1 = *(const float4*)&aSrc[kg + af * 4 + 32];
            pa2 = *(const float4*)&aSrc[kg + af * 4 + 64];
            pa3 = *(const float4*)&aSrc[kg + af * 4 + 96];
        }
        // compute: two 64-k halves, thread's 4-k slice each
#pragma unroll
        for (int h = 0; h < 2; ++h) {
            float4 ar[8], bc[8];
            const int ka = h * 64 + ks * 4;
            const int kb = c * 128 + h * 64 + ks * 4;
#pragma unroll
            for (int rr = 0; rr < 8; ++rr)
                ar[rr] = *(const float4*)&Aw[rr * ASTR + ka];
#pragma unroll
            for (int cc = 0; cc < 8; ++cc)
                bc[cc] = *(const float4*)&Bs[(cpair * 8 + cc) * BSTR + kb];
#pragma unroll
            for (int rr = 0; rr < 8; ++rr)
#pragma unroll
                for (int cc = 0; cc < 8; ++cc)
                    acc[rr][cc] += ar[rr].x * bc[cc].x + ar[rr].y * bc[cc].y
                                 + ar[rr].z * bc[cc].z + ar[rr].w * bc[cc].w;
        }
    }

    // ---- reduce: fold ks low-2 bits via shfl (lane bits 2,3) ----
#pragma unroll
    for (int rr = 0; rr < 8; ++rr)
#pragma unroll
        for (int cc = 0; cc < 8; ++cc) {
            float v = acc[rr][cc];
            v += __shfl_xor(v, 4);
            v += __shfl_xor(v, 8);
            acc[rr][cc] = v;
        }

    // writers: lanes with (ks & 3) == 0, i.e. (lane & 12) == 0.
    // layout (float4 units): [(ksg*4 + cpair)*16 + rr*2 + half]
    if ((lane & 12) == 0) {
        const int ksg = lane >> 4;
        float* w = Aw + ((ksg * 4 + cpair) << 6);
#pragma unroll
        for (int rr = 0; rr < 8; ++rr) {
            *(float4*)&w[rr * 8]     = make_float4(acc[rr][0], acc[rr][1], acc[rr][2], acc[rr][3]);
            *(float4*)&w[rr * 8 + 4] = make_float4(acc[rr][4], acc[rr][5], acc[rr][6], acc[rr][7]);
        }
    }
    // readers (same wave; lgkmcnt orders): lane -> (rr, cc4, cp)
    {
        const int out_rr = lane >> 3, out_cc4 = (lane >> 2) & 1, out_cp = lane & 3;
        const int off = out_rr * 8 + out_cc4 * 4;
        float4 s0 = *(const float4*)&Aw[((0 * 4 + out_cp) << 6) + off];
        float4 s1 = *(const float4*)&Aw[((1 * 4 + out_cp) << 6) + off];
        float4 s2 = *(const float4*)&Aw[((2 * 4 + out_cp) << 6) + off];
        float4 s3 = *(const float4*)&Aw[((3 * 4 + out_cp) << 6) + off];
        float z0 = s0.x + s1.x + s2.x + s3.x;
        float z1 = s0.y + s1.y + s2.y + s3.y;
        float z2 = s0.z + s1.z + s2.z + s3.z;
        float z3 = s0.w + s1.w + s2.w + s3.w;

        const int grow = r0 + wv * 8 + out_rr;
        const int dcol = dbase + out_cp * 8 + out_cc4 * 4;
        float4 cv = *(const float4*)&cvec[l * 256 + dcol];
        z0 += cv.x; z1 += cv.y; z2 += cv.z; z3 += cv.w;
        if (l == 0) {
            float4 rc = *(const float4*)&rc0[(size_t)grow * 256 + dcol];
            z0 += rc.x; z1 += rc.y; z2 += rc.z; z3 += rc.w;
        }
        float4 rold = *(const float4*)&rcur[(size_t)grow * 1024 + l * 256 + dcol];
        float4 o;
        o.x = rold.x + 0.1f * tanhf(z0);
        o.y = rold.y + 0.1f * tanhf(z1);
        o.z = rold.z + 0.1f * tanhf(z2);
        o.w = rold.w + 0.1f * tanhf(z3);
        *(float4*)&rnxt[(size_t)grow * 1024 + l * 256 + dcol] = o;
    }
}

// ---------------------------------------------------------------------------
// k_heads: per-row head computations (refined, sqk/eqk/sqb/eqb, answerable).
// ---------------------------------------------------------------------------
__global__ __launch_bounds__(256) void k_heads(const float* __restrict__ rA,
    const float* __restrict__ ff,
    const float* __restrict__ KSt, const float* __restrict__ KEt,
    const float* __restrict__ ksb, const float* __restrict__ keb,
    const float* __restrict__ vsk, const float* __restrict__ vse,
    const float* __restrict__ scal,
    const float* __restrict__ W1t, const float* __restrict__ b1,
    const float* __restrict__ w2, const float* __restrict__ b2,
    float* __restrict__ sqk, float* __restrict__ eqk,
    float* __restrict__ sqb, float* __restrict__ eqb,
    float* __restrict__ out)
{
    const int row = blockIdx.x, t = threadIdx.x;
    __shared__ float xs[256];
    __shared__ float red[256];
    __shared__ float hp[256];
    __shared__ float hs[128];
    xs[t] = rA[(size_t)row * 1024 + 768 + t] + ff[(size_t)row * 256 + t];
    __syncthreads();
    {
        float a0 = 0.f, a1 = 0.f, a2 = 0.f, a3 = 0.f;
        float e0 = 0.f, e1 = 0.f, e2 = 0.f, e3 = 0.f;
        const float* KS = KSt + t;
        const float* KE = KEt + t;
#pragma unroll 4
        for (int f = 0; f < 256; f += 4) {
            float4 xv = *(const float4*)&xs[f];
            a0 += KS[(size_t)(f + 0) * 256] * xv.x; a1 += KS[(size_t)(f + 1) * 256] * xv.y;
            a2 += KS[(size_t)(f + 2) * 256] * xv.z; a3 += KS[(size_t)(f + 3) * 256] * xv.w;
            e0 += KE[(size_t)(f + 0) * 256] * xv.x; e1 += KE[(size_t)(f + 1) * 256] * xv.y;
            e2 += KE[(size_t)(f + 2) * 256] * xv.z; e3 += KE[(size_t)(f + 3) * 256] * xv.w;
        }
        sqk[(size_t)row * 256 + t] = a0 + a1 + a2 + a3 + ksb[t];
        eqk[(size_t)row * 256 + t] = e0 + e1 + e2 + e3 + keb[t];
    }
    red[t] = vsk[t] * xs[t];
    __syncthreads();
    for (int s = 128; s > 0; s >>= 1) { if (t < s) red[t] += red[t + s]; __syncthreads(); }
    if (t == 0) sqb[row] = red[0] + scal[0];
    __syncthreads();
    red[t] = vse[t] * xs[t];
    __syncthreads();
    for (int s = 128; s > 0; s >>= 1) { if (t < s) red[t] += red[t + s]; __syncthreads(); }
    if (t == 0) eqb[row] = red[0] + scal[1];
    __syncthreads();
    {
        const int j = t & 127, half = t >> 7;
        float a = 0.f;
        const float* W = W1t + (size_t)half * 128 * 128 + j;
        const float* xh = &xs[half * 128];
#pragma unroll 8
        for (int e = 0; e < 128; ++e) a += W[(size_t)e * 128] * xh[e];
        hp[half * 128 + j] = a;
    }
    __syncthreads();
    if (t < 128) {
        float x = hp[t] + hp[128 + t] + b1[t];
        hs[t] = 0.5f * x * (1.f + erff(x * 0.70710678118654752f));
    }
    __syncthreads();
    if (t < 128) { red[t] = hs[t] * w2[t]; red[128 + t] = hs[t] * w2[128 + t]; }
    __syncthreads();
    for (int s = 64; s > 0; s >>= 1) {
        if (t < s) red[t] += red[t + s];
        else if (t >= 128 && t < 128 + s) red[t] += red[t + s];
        __syncthreads();
    }
    if (t == 0)   out[2 * NB * NS + row * 2 + 0] = red[0] + b2[0];
    if (t == 128) out[2 * NB * NS + row * 2 + 1] = red[128] + b2[1];
}

// ---------------------------------------------------------------------------
// logits gather
// ---------------------------------------------------------------------------
__global__ __launch_bounds__(512) void k_logits(const int* __restrict__ ids,
                                                const float* __restrict__ emb,
                                                const float* __restrict__ pos,
                                                const float* __restrict__ sqk,
                                                const float* __restrict__ eqk,
                                                const float* __restrict__ sqb,
                                                const float* __restrict__ eqb,
                                                float* __restrict__ out) {
    const int bid = blockIdx.x;
    const int b = bid >> 2, q = bid & 3;
    const int t = threadIdx.x;
    __shared__ float sk[ND], ek[ND];
    __shared__ int sid[128];
    if (t < 256) sk[t] = sqk[b * ND + t];
    else ek[t - 256] = eqk[b * ND + t - 256];
    if (t < 128) sid[t] = ids[b * NS + q * 128 + t];
    __syncthreads();
    const int w = t >> 6, lane = t & 63;
    const float4 ks = *(const float4*)&sk[4 * lane];
    const float4 ke = *(const float4*)&ek[4 * lane];
    const float qbs = sqb[b], qbe = eqb[b];
    for (int si = w; si < 128; si += 8) {
        const int s = q * 128 + si;
        const int id = sid[si];
        const float4 e4 = *(const float4*)&emb[(size_t)id * ND + 4 * lane];
        const float4 p4 = *(const float4*)&pos[s * ND + 4 * lane];
        float vx = e4.x + p4.x, vy = e4.y + p4.y, vz = e4.z + p4.z, vw = e4.w + p4.w;
        float ds = vx * ks.x + vy * ks.y + vz * ks.z + vw * ks.w;
        float de = vx * ke.x + vy * ke.y + vz * ke.z + vw * ke.w;
#pragma unroll
        for (int off = 32; off >= 1; off >>= 1) {
            ds += __shfl_xor(ds, off);
            de += __shfl_xor(de, off);
        }
        if (lane == 0) {
            out[b * NS + s] = ds + qbs;
            out[NB * NS + b * NS + s] = de + qbe;
        }
    }
}

// ---------------------------------------------------------------------------
extern "C" void kernel_launch(void* const* d_in, const int* in_sizes, int n_in,
                              void* d_out, int out_size, void* d_ws, size_t ws_size,
                              hipStream_t stream) {
    const int*   ids    = (const int*)d_in[0];
    const float* emb    = (const float*)d_in[1];
    const float* pos    = (const float*)d_in[2];
    const float* init_w = (const float*)d_in[3];
    const float* init_b = (const float*)d_in[4];
    const float* pred_w = (const float*)d_in[5];
    const float* pred_b = (const float*)d_in[6];
    const float* upd_w  = (const float*)d_in[7];
    const float* upd_b  = (const float*)d_in[8];
    const float* sw     = (const float*)d_in[9];
    const float* sb     = (const float*)d_in[10];
    const float* ew     = (const float*)d_in[11];
    const float* eb     = (const float*)d_in[12];
    const float* kw     = (const float*)d_in[13];
    const float* kb     = (const float*)d_in[14];
    const float* w1     = (const float*)d_in[15];
    const float* b1     = (const float*)d_in[16];
    const float* w2     = (const float*)d_in[17];
    const float* b2     = (const float*)d_in[18];
    float* out = (float*)d_out;

    float* ws = (float*)d_ws;
    float* partial = ws;                 ws += 1024 * 256;
    float* rA      = ws;                 ws += 256 * 1024;
    float* rB      = ws;                 ws += 256 * 1024;
    float* ff      = ws;                 ws += 256 * 256;
    float* CM      = ws;                 ws += 12 * DD;
    float* CMI     = ws;                 ws += 4 * DD;
    float* KSt     = ws;                 ws += DD;
    float* KEt     = ws;                 ws += DD;
    float* W1t     = ws;                 ws += 256 * 128;
    float* cvec    = ws;                 ws += 4 * 256;
    float* rc0     = ws;                 ws += 256 * 256;
    float* vsk     = ws;                 ws += 256;
    float* vse     = ws;                 ws += 256;
    float* ksb     = ws;                 ws += 256;
    float* keb     = ws;                 ws += 256;
    float* scal    = ws;                 ws += 8;
    float* sqk     = ws;                 ws += 256 * 256;
    float* eqk     = ws;                 ws += 256 * 256;
    float* sqb     = ws;                 ws += 256;
    float* eqb     = ws;                 ws += 256;

    k_pool1<<<1024, 256, 0, stream>>>(ids, emb, pos, partial);

    k_prep<<<1126, 256, 0, stream>>>(pred_w, pred_b, upd_w, upd_b, init_w,
                                     sw, sb, ew, eb, kw, kb, w1, partial,
                                     CM, CMI, KSt, KEt, W1t,
                                     cvec, rc0, vsk, vse, ksb, keb, scal);

    k_init<<<256, 256, 0, stream>>>(partial, CMI, init_b, rA, ff);

    float* cur = rA;
    float* nxt = rB;
    for (int it = 0; it < NITERS; ++it) {
        k_stage<<<256, 256, 0, stream>>>(cur, CM, cvec, rc0, nxt);
        float* tmp = cur; cur = nxt; nxt = tmp;
    }
    // NITERS even -> final reps in rA

    k_heads<<<256, 256, 0, stream>>>(rA, ff, KSt, KEt, ksb, keb, vsk, vse, scal,
                                     W1t, b1, w2, b2, sqk, eqk, sqb, eqb, out);

    k_logits<<<1024, 512, 0, stream>>>(ids, emb, pos, sqk, eqk, sqb, eqb, out);
}